// Round 7
// baseline (538.895 us; speedup 1.0000x reference)
//
#include <hip/hip_runtime.h>
#include <hip/hip_bf16.h>
#include <stdint.h>

#define T_SEQ 8192
#define B_SZ 2
#define CDIM 1024
#define NH 16
#define HDIM 64
#define NW 32

typedef unsigned short ushort_t;
typedef __attribute__((ext_vector_type(8))) short short8;     // 8 bf16 (4 VGPRs) MFMA A/B frag
typedef __attribute__((ext_vector_type(8))) unsigned short us8;
typedef __attribute__((ext_vector_type(4))) unsigned short us4;
typedef __attribute__((ext_vector_type(4))) float f32x4;      // MFMA C/D frag

__device__ __forceinline__ unsigned short f2bf(float f) {
  union { float f; unsigned int u; } c; c.f = f;
  return (unsigned short)((c.u + 0x7FFFu + ((c.u >> 16) & 1u)) >> 16);
}
__device__ __forceinline__ unsigned pk2(float a, float b) {
  unsigned r;
  asm("v_cvt_pk_bf16_f32 %0, %1, %2" : "=v"(r) : "v"(a), "v"(b));
  return r;   // low16 = bf16(a), high16 = bf16(b), RTNE
}
__device__ __forceinline__ void gld16(void* lds, const void* g) {
  __builtin_amdgcn_global_load_lds(
      (const __attribute__((address_space(1))) void*)g,
      (__attribute__((address_space(3))) void*)lds, 16, 0, 0);
}

// ---------------- fp32 -> bf16 conversion (RTNE) ----------------
__global__ __launch_bounds__(256) void cvt_f32_bf16(const float* __restrict__ src,
                                                    ushort_t* __restrict__ dst, int n4)
{
  int i = blockIdx.x * 256 + threadIdx.x;
  if (i < n4) {
    float4 v = ((const float4*)src)[i];
    ushort4 o;
    o.x = f2bf(v.x); o.y = f2bf(v.y); o.z = f2bf(v.z); o.w = f2bf(v.w);
    ((ushort4*)dst)[i] = o;
  }
}

// all 4 weight matrices into one contiguous bf16 buffer (rows 0..4095); grid (1024, 4)
__global__ __launch_bounds__(256) void cvt_w4(const float* __restrict__ w0,
                                              const float* __restrict__ w1,
                                              const float* __restrict__ w2,
                                              const float* __restrict__ w3,
                                              ushort_t* __restrict__ dst)
{
  const float* srcs[4] = {w0, w1, w2, w3};
  const float* s = srcs[blockIdx.y];
  ushort_t* d = dst + (size_t)blockIdx.y * CDIM * CDIM;
  int i = blockIdx.x * 256 + threadIdx.x;
  float4 v = ((const float4*)s)[i];
  ushort4 o;
  o.x = f2bf(v.x); o.y = f2bf(v.y); o.z = f2bf(v.z); o.w = f2bf(v.w);
  ((ushort4*)d)[i] = o;
}

// ---------------- 256x256 BK=64 double-buffered 2-phase GEMM core ----------------
// ROUND-5 EXACT (measured 129.9 us / 793 TF for qkv). Round-6's counted-vmcnt + second
// barrier regressed 7% (graft without per-phase interleave = pure barrier overhead).
// 512 threads = 8 waves (2M x 4N). Per-wave output 128x64 (acc[8][4]).
// LDS (dynamic, 128 KB): As[2][256*64] + Bs[2][256*64], XOR-swizzled 16B blocks.
// Per K-tile: issue next tile's 8 gld16 FIRST, then ds_read+64 MFMA on current buffer,
// then one __syncthreads() (vmcnt0+lgkm0+barrier) — staging hides under compute.
__device__ __forceinline__ void gemm256_core(const ushort_t* __restrict__ A,
                                             const ushort_t* __restrict__ W,
                                             ushort_t* SH,
                                             int m0, int n0, int t, f32x4 acc[8][4])
{
  const int lane = t & 63;
  const int wv = t >> 6;          // 0..7
  const int wr = wv >> 2;         // 0..1  (M half)
  const int wc = wv & 3;          // 0..3  (N quarter)
  const int fr = lane & 15;
  const int quad = lane >> 4;

  ushort_t* As = SH;              // [2][16384]
  ushort_t* Bs = SH + 32768;

  const int sr8 = lane >> 3;                     // 0..7 == staged row & 7
  const int scb = ((lane & 7) ^ sr8) * 8;        // pre-swizzled source col (elems)
  const int srowb = wv * 8 + sr8;                // base staged row (0..63, +p*64)
  const ushort_t* Ag = A + (size_t)(m0 + srowb) * CDIM + scb;
  const ushort_t* Wg = W + (size_t)(n0 + srowb) * CDIM + scb;
  ushort_t* lA = As + srowb * 64 + (lane & 7) * 8;   // linear in lane within a wave
  ushort_t* lB = Bs + srowb * 64 + (lane & 7) * 8;

  // prologue: stage kt=0 into buf 0
#pragma unroll
  for (int p = 0; p < 4; p++) {
    gld16(lA + p * 4096, Ag + (size_t)p * 64 * CDIM);
    gld16(lB + p * 4096, Wg + (size_t)p * 64 * CDIM);
  }
  __syncthreads();

  for (int kt = 0; kt < CDIM / 64; ++kt) {
    const int cur = kt & 1;
    if (kt + 1 < CDIM / 64) {     // issue next tile BEFORE compute (latency hides under MFMA)
      const ushort_t* Agn = Ag + (kt + 1) * 64;
      const ushort_t* Wgn = Wg + (kt + 1) * 64;
      ushort_t* nA = lA + (cur ^ 1) * 16384;
      ushort_t* nB = lB + (cur ^ 1) * 16384;
#pragma unroll
      for (int p = 0; p < 4; p++) {
        gld16(nA + p * 4096, Agn + (size_t)p * 64 * CDIM);
        gld16(nB + p * 4096, Wgn + (size_t)p * 64 * CDIM);
      }
    }
    const ushort_t* Ac = As + cur * 16384;
    const ushort_t* Bc = Bs + cur * 16384;
    short8 b[4][2];
#pragma unroll
    for (int j = 0; j < 4; j++)
#pragma unroll
      for (int ks = 0; ks < 2; ks++)
        b[j][ks] = *(const short8*)&Bc[(wc * 64 + j * 16 + fr) * 64 +
                                       (((ks * 4 + quad) ^ (fr & 7)) * 8)];
    __builtin_amdgcn_s_setprio(1);
#pragma unroll
    for (int i = 0; i < 8; i++) {
      const int ra = (wr * 128 + i * 16 + fr) * 64;
      short8 a0 = *(const short8*)&Ac[ra + ((quad ^ (fr & 7)) * 8)];
      short8 a1 = *(const short8*)&Ac[ra + (((4 + quad) ^ (fr & 7)) * 8)];
#pragma unroll
      for (int j = 0; j < 4; j++)
        acc[i][j] = __builtin_amdgcn_mfma_f32_16x16x32_bf16(a0, b[j][0], acc[i][j], 0, 0, 0);
#pragma unroll
      for (int j = 0; j < 4; j++)
        acc[i][j] = __builtin_amdgcn_mfma_f32_16x16x32_bf16(a1, b[j][1], acc[i][j], 0, 0, 0);
    }
    __builtin_amdgcn_s_setprio(0);
    __syncthreads();              // vmcnt(0)+lgkmcnt(0)+barrier: next tile landed, reads done
  }
}

// XCD-chunked bijective block swizzle (nwg % 8 == 0 for all our grids)
__device__ __forceinline__ void xcd_swz(int& bx, int& by) {
  int gx = gridDim.x, nwg = gx * gridDim.y;
  int lid = bx + gx * by;
  int cpx = nwg >> 3;
  int swz = (lid & 7) * cpx + (lid >> 3);
  bx = swz % gx;
  by = swz / gx;
}

// ---------------- fused QKV projection: N=3072, per-section epilogue ----------------
// grid (12, 64), 512 threads, 128 KB dynamic LDS. sections: bx>>2 -> 0=Q 1=K 2=V.
__global__ __launch_bounds__(512, 1) void gemm_qkv(const ushort_t* __restrict__ A,
                                                   const ushort_t* __restrict__ Wcat,
                                                   const float* __restrict__ bq,
                                                   const float* __restrict__ bk,
                                                   const float* __restrict__ bv,
                                                   ushort_t* __restrict__ Qb,
                                                   ushort_t* __restrict__ Kb,
                                                   ushort_t* __restrict__ Vtb,
                                                   const float* __restrict__ cosT,
                                                   const float* __restrict__ sinT)
{
  extern __shared__ ushort_t SH[];   // 131072 B: K-loop dbuf tiles; epilogue 128x264 retile

  const int t = threadIdx.x;
  const int lane = t & 63;
  const int wv = t >> 6;
  const int wr = wv >> 2;
  const int wc = wv & 3;
  const int fr = lane & 15;
  const int quad = lane >> 4;
  int bx = blockIdx.x, by = blockIdx.y;
  xcd_swz(bx, by);
  const int m0 = by * 256;
  const int n0 = bx * 256;              // row in Wcat (0..3071)
  const int sec = bx >> 2;              // 0=Q 1=K 2=V
  const int nsec0 = (bx & 3) * 256;
  const float* bias = (sec == 0) ? bq : (sec == 1) ? bk : bv;

  f32x4 acc[8][4];
#pragma unroll
  for (int i = 0; i < 8; i++)
#pragma unroll
    for (int j = 0; j < 4; j++) acc[i][j] = (f32x4){0.f, 0.f, 0.f, 0.f};

  gemm256_core(A, Wcat, SH, m0, n0, t, acc);

  if (sec < 2) {
    // RoPE in C-layout regs -> LDS retile (stride 264) in two 128-row passes -> us8 stores
    ushort_t* OutQK = sec ? Kb : Qb;
#pragma unroll
    for (int half = 0; half < 2; ++half) {
      if (wr == half) {
#pragma unroll
        for (int jp = 0; jp < 2; jp++) {
          int d = jp * 16 + fr;               // head-dim lo (0..31)
          int cl = wc * 64 + jp * 16 + fr;    // col in 256-tile
          float bl = bias[nsec0 + cl];
          float bh = bias[nsec0 + cl + 32];
#pragma unroll
          for (int i = 0; i < 8; i++) {
            int rloc = i * 16 + quad * 4;     // row within the 128-row half
#pragma unroll
            for (int r = 0; r < 4; r++) {
              int m = m0 + half * 128 + rloc + r;
              int tt = m & (T_SEQ - 1);
              float c = cosT[tt * HDIM + d];
              float sn = sinT[tt * HDIM + d];
              float lo = acc[i][jp][r] + bl;
              float hi = acc[i][jp + 2][r] + bh;
              SH[(rloc + r) * 264 + cl] = f2bf(lo * c - hi * sn);
              SH[(rloc + r) * 264 + cl + 32] = f2bf(hi * c + lo * sn);
            }
          }
        }
      }
      __syncthreads();
      const int rr0 = t >> 5;                 // 0..15
      const int c8 = (t & 31) * 8;            // 0..248
      size_t gbase = (size_t)(m0 + half * 128) * CDIM + nsec0 + c8;
#pragma unroll
      for (int pp = 0; pp < 8; pp++) {
        int rr = pp * 16 + rr0;
        *(us8*)&OutQK[gbase + (size_t)rr * CDIM] = *(const us8*)&SH[rr * 264 + c8];
      }
      __syncthreads();
    }
  } else {
    // V -> Vt[b][ch][tok], 4 consecutive tokens per 8B store
#pragma unroll
    for (int j = 0; j < 4; j++) {
      int ch = nsec0 + wc * 64 + j * 16 + fr;
      float bvv = bias[ch];
#pragma unroll
      for (int i = 0; i < 8; i++) {
        int m = m0 + wr * 128 + i * 16 + quad * 4;
        int bb = m >> 13;
        int tq = m & (T_SEQ - 1);
        us4 pk;
#pragma unroll
        for (int r = 0; r < 4; r++) pk[r] = f2bf(acc[i][j][r] + bvv);
        *(us4*)&Vtb[((size_t)bb * CDIM + ch) * T_SEQ + tq] = pk;
      }
    }
  }
}

// ---------------- output projection: bf16 in, fp32 out; grid (4, 64) ----------------
__global__ __launch_bounds__(512, 1) void gemm_out(const ushort_t* __restrict__ A,
                                                   const ushort_t* __restrict__ W,
                                                   const float* __restrict__ bias,
                                                   float* __restrict__ Out)
{
  extern __shared__ ushort_t SH[];

  const int t = threadIdx.x;
  const int lane = t & 63;
  const int wv = t >> 6;
  const int wr = wv >> 2;
  const int wc = wv & 3;
  const int fr = lane & 15;
  const int quad = lane >> 4;
  int bx = blockIdx.x, by = blockIdx.y;
  xcd_swz(bx, by);
  const int m0 = by * 256;
  const int n0 = bx * 256;

  f32x4 acc[8][4];
#pragma unroll
  for (int i = 0; i < 8; i++)
#pragma unroll
    for (int j = 0; j < 4; j++) acc[i][j] = (f32x4){0.f, 0.f, 0.f, 0.f};

  gemm256_core(A, W, SH, m0, n0, t, acc);

#pragma unroll
  for (int j = 0; j < 4; j++) {
    int n = n0 + wc * 64 + j * 16 + fr;
    float bvv = bias[n];
#pragma unroll
    for (int i = 0; i < 8; i++) {
      int m = m0 + wr * 128 + i * 16 + quad * 4;
#pragma unroll
      for (int r = 0; r < 4; r++)
        Out[(size_t)(m + r) * CDIM + n] = acc[i][j][r] + bvv;
    }
  }
}

// ---------------- windowed attention, flash-style over 8 chunks of 64 keys ----------------
// Round-1 structure (known ~120 us) with ONE change: PsW halved to per-wave 16 rows
// (softmax->pack->PV fused per mt-group; per-wave DS ops are in-order so the mt=0-read /
// mt=1-write WAR is safe — validated in round 3). LDS 37.4 -> 28.7 KB => 5 blocks/CU.
__global__ __launch_bounds__(256, 4) void attn_kernel(const ushort_t* __restrict__ Q,
                                                      const ushort_t* __restrict__ Kg,
                                                      const ushort_t* __restrict__ Vt,
                                                      const int* __restrict__ mask,
                                                      ushort_t* __restrict__ AO)
{
  __shared__ ushort_t Ks[64 * 72];            //  9216 B  [key][dim]
  __shared__ ushort_t Vts[64 * 72];           //  9216 B  [dim][key]
  __shared__ unsigned int PsW[4 * 16 * 32];   //  8192 B  per-wave 16 rows x 32 words, XOR-swz
  __shared__ float attf[512];                 //  2048 B  additive key bias (0 / -1e38)

  const int t = threadIdx.x;
  const int lane = t & 63;
  const int wv = t >> 6;
  const int h = blockIdx.x;
  const int w = blockIdx.y >> 1;
  const int qh = blockIdx.y & 1;
  const int b = blockIdx.z;
  const int fr = lane & 15;
  const int quad = lane >> 4;

  {
    int p0 = w * 256 + t - 128;
    bool a0 = (p0 < 0 || p0 >= T_SEQ) ? true : (mask[b * T_SEQ + p0] == 0);
    int p1 = p0 + 256;
    bool a1 = (p1 < 0 || p1 >= T_SEQ) ? true : (mask[b * T_SEQ + p1] == 0);
    int all1 = __syncthreads_and((int)(a0 && a1));
    attf[t] = a0 ? 0.f : -1.0e38f;
    attf[t + 256] = a1 ? 0.f : -1.0e38f;
    if (all1 && t == 0) attf[0] = -1.0e38f;   // reference quirk: fully-attendable -> mask key 0
  }

  // Q -> registers (B-frag of QK^T): lane holds Q[mt*16+fr][ks*32+quad*8 ..+7]
  short8 qf[2][2];
  {
    const ushort_t* qp = Q + ((size_t)b * T_SEQ + w * 256 + qh * 128 + wv * 32 + fr) * CDIM
                           + h * HDIM + quad * 8;
#pragma unroll
    for (int mt = 0; mt < 2; mt++)
#pragma unroll
      for (int ks = 0; ks < 2; ks++)
        qf[mt][ks] = *(const short8*)&qp[(size_t)mt * 16 * CDIM + ks * 32];
  }

  const int srow = t >> 3;                    // 0..31
  const int sc8 = (t & 7) * 8;
  const ushort_t* kgb = Kg + (size_t)b * T_SEQ * CDIM + h * HDIM + sc8;
  const ushort_t* vt_base = Vt + ((size_t)b * CDIM + h * HDIM) * T_SEQ;
  const float SCL = 0.18033688011112042f;     // 0.125 * log2(e)

  unsigned int* pw = &PsW[wv * 512];
  const int swz = (fr & 7) << 2;
  const int rbase = quad << 2;

  float m_run[2], l_run[2];
  f32x4 o[2][4];
#pragma unroll
  for (int mt = 0; mt < 2; mt++) { m_run[mt] = -3.0e38f; l_run[mt] = 0.f; }
#pragma unroll
  for (int mt = 0; mt < 2; mt++)
#pragma unroll
    for (int nt = 0; nt < 4; nt++) o[mt][nt] = (f32x4){0.f, 0.f, 0.f, 0.f};

  for (int kc = 0; kc < 8; kc++) {
    __syncthreads();
    {
#pragma unroll
      for (int p = 0; p < 2; p++) {
        int jj = p * 32 + srow;
        int pos = w * 256 + kc * 64 + jj - 128;
        us8 kval = (us8)(0);
        if (pos >= 0 && pos < T_SEQ) kval = *(const us8*)&kgb[(size_t)pos * CDIM];
        *(us8*)&Ks[jj * 72 + sc8] = kval;
      }
      int pos0 = w * 256 + kc * 64 - 128 + sc8;
      bool inr = (pos0 >= 0) && (pos0 < T_SEQ);
#pragma unroll
      for (int p = 0; p < 2; p++) {
        int d = p * 32 + srow;
        us8 vv = (us8)(0);
        if (inr) vv = *(const us8*)&vt_base[(size_t)d * T_SEQ + pos0];
        *(us8*)&Vts[d * 72 + sc8] = vv;
      }
    }
    __syncthreads();

    // S^T = K·Q^T : lane holds key = nt*16+quad*4+r, q-row = mt*16+fr
    short8 kf[4][2];
#pragma unroll
    for (int nt = 0; nt < 4; nt++)
#pragma unroll
      for (int ks = 0; ks < 2; ks++)
        kf[nt][ks] = *(const short8*)&Ks[(nt * 16 + fr) * 72 + ks * 32 + quad * 8];

    f32x4 st[2][4];
    __builtin_amdgcn_s_setprio(1);
#pragma unroll
    for (int mt = 0; mt < 2; mt++)
#pragma unroll
      for (int nt = 0; nt < 4; nt++) {
        f32x4 a = (f32x4){0.f, 0.f, 0.f, 0.f};
        a = __builtin_amdgcn_mfma_f32_16x16x32_bf16(kf[nt][0], qf[mt][0], a, 0, 0, 0);
        a = __builtin_amdgcn_mfma_f32_16x16x32_bf16(kf[nt][1], qf[mt][1], a, 0, 0, 0);
        st[mt][nt] = a;
      }
    __builtin_amdgcn_s_setprio(0);

    // scale + mask fused (exp2 domain); kb[nt][r] is key 16nt+4*quad+r
    f32x4 kb[4];
#pragma unroll
    for (int nt = 0; nt < 4; nt++)
      kb[nt] = *(const f32x4*)&attf[kc * 64 + nt * 16 + quad * 4];
#pragma unroll
    for (int mt = 0; mt < 2; mt++)
#pragma unroll
      for (int nt = 0; nt < 4; nt++)
#pragma unroll
        for (int r = 0; r < 4; r++)
          st[mt][nt][r] = __builtin_fmaf(st[mt][nt][r], SCL, kb[nt][r]);

    // V frags (mt-independent) hoisted before the fused per-mt loop
    short8 vf[4][2];
#pragma unroll
    for (int nt = 0; nt < 4; nt++)
#pragma unroll
      for (int ks = 0; ks < 2; ks++)
        vf[nt][ks] = *(const short8*)&Vts[(nt * 16 + fr) * 72 + ks * 32 + quad * 8];

    // per-mt: lane-local online softmax (rows mt*16+fr, defer-max THR=8) -> pack -> PV
#pragma unroll
    for (int mt = 0; mt < 2; mt++) {
      float t0 = fmaxf(fmaxf(st[mt][0][0], st[mt][0][1]), fmaxf(st[mt][0][2], st[mt][0][3]));
      float t1 = fmaxf(fmaxf(st[mt][1][0], st[mt][1][1]), fmaxf(st[mt][1][2], st[mt][1][3]));
      float t2 = fmaxf(fmaxf(st[mt][2][0], st[mt][2][1]), fmaxf(st[mt][2][2], st[mt][2][3]));
      float t3 = fmaxf(fmaxf(st[mt][3][0], st[mt][3][1]), fmaxf(st[mt][3][2], st[mt][3][3]));
      float mx = fmaxf(fmaxf(t0, t1), fmaxf(t2, t3));
      mx = fmaxf(mx, __shfl_xor(mx, 16, 64));
      mx = fmaxf(mx, __shfl_xor(mx, 32, 64));
      if (!__all(mx <= m_run[mt] + 8.f)) {
        float mnew = fmaxf(m_run[mt], mx);
        float alpha = __builtin_amdgcn_exp2f(m_run[mt] - mnew);
        m_run[mt] = mnew;
        l_run[mt] *= alpha;
        float af[4];
#pragma unroll
        for (int r = 0; r < 4; r++) af[r] = __shfl(alpha, rbase + r, 64);
#pragma unroll
        for (int nt = 0; nt < 4; nt++)
#pragma unroll
          for (int r = 0; r < 4; r++) o[mt][nt][r] *= af[r];
      }
      float rs = 0.f;
#pragma unroll
      for (int nt = 0; nt < 4; nt++)
#pragma unroll
        for (int r = 0; r < 4; r++) {
          float p = __builtin_amdgcn_exp2f(st[mt][nt][r] - m_run[mt]);
          st[mt][nt][r] = p;
          rs += p;
        }
      rs += __shfl_xor(rs, 16, 64);
      rs += __shfl_xor(rs, 32, 64);
      l_run[mt] += rs;

      // pack P row fr -> per-wave 16-row exchange buffer (word w=8nt+2q+h holds keys 2w,2w+1)
      unsigned int* pr = pw + (fr << 5);
#pragma unroll
      for (int nt = 0; nt < 4; nt++)
#pragma unroll
        for (int hh = 0; hh < 2; hh++)
          pr[(((nt << 3) + (quad << 1) + hh)) ^ swz] =
              pk2(st[mt][nt][2 * hh], st[mt][nt][2 * hh + 1]);

      // read back as A-frag (keys ks*32+quad*8 ..+7 of row fr)
      short8 pf[2];
#pragma unroll
      for (int ks = 0; ks < 2; ks++)
        pf[ks] = *(const short8*)&pr[((ks << 4) + (quad << 2)) ^ swz];

      __builtin_amdgcn_s_setprio(1);
#pragma unroll
      for (int nt = 0; nt < 4; nt++) {
        o[mt][nt] = __builtin_amdgcn_mfma_f32_16x16x32_bf16(pf[0], vf[nt][0], o[mt][nt], 0, 0, 0);
        o[mt][nt] = __builtin_amdgcn_mfma_f32_16x16x32_bf16(pf[1], vf[nt][1], o[mt][nt], 0, 0, 0);
      }
      __builtin_amdgcn_s_setprio(0);
    }
  }

  // epilogue: o rows = wv*32 + mt*16 + quad*4 + r; pull 1/l from the lane owning that row
  size_t obase = ((size_t)b * T_SEQ + w * 256 + qh * 128 + wv * 32) * CDIM + h * HDIM;
#pragma unroll
  for (int mt = 0; mt < 2; mt++)
#pragma unroll
    for (int r = 0; r < 4; r++) {
      float lv = __shfl(l_run[mt], rbase + r, 64);
      float iv = 1.0f / fmaxf(lv, 1e-30f);
      int row = mt * 16 + quad * 4 + r;
#pragma unroll
      for (int nt = 0; nt < 4; nt++)
        AO[obase + (size_t)row * CDIM + nt * 16 + fr] = f2bf(o[mt][nt][r] * iv);
    }
}

extern "C" void kernel_launch(void* const* d_in, const int* in_sizes, int n_in,
                              void* d_out, int out_size, void* d_ws, size_t ws_size,
                              hipStream_t stream)
{
  const float* x    = (const float*)d_in[0];
  const int*   pm   = (const int*)d_in[1];
  const float* cosT = (const float*)d_in[2];
  const float* sinT = (const float*)d_in[3];
  const float* Wq   = (const float*)d_in[4];
  const float* bq   = (const float*)d_in[5];
  const float* Wk   = (const float*)d_in[6];
  const float* bk   = (const float*)d_in[7];
  const float* Wv   = (const float*)d_in[8];
  const float* bv   = (const float*)d_in[9];
  const float* Wo   = (const float*)d_in[10];
  const float* bo   = (const float*)d_in[11];
  float* out = (float*)d_out;

  static bool attr_done = false;
  if (!attr_done) {
    hipFuncSetAttribute(reinterpret_cast<const void*>(gemm_qkv),
                        hipFuncAttributeMaxDynamicSharedMemorySize, 131072);
    hipFuncSetAttribute(reinterpret_cast<const void*>(gemm_out),
                        hipFuncAttributeMaxDynamicSharedMemorySize, 131072);
    attr_done = true;
  }

  // scratch layout:
  //   d_out lower half : K (bf16)       — dead before final GEMM overwrites d_out
  //   d_out upper half : x_bf (bf16)    — dead after QKV projection
  //   ws: Wcat bf16 [Wq;Wk;Wv;Wo] (8 MB) + Q (33.5) + Vt (33.5, [b][ch][tok])
  const size_t NTOK = (size_t)B_SZ * T_SEQ;
  const size_t NELT = NTOK * CDIM;
  ushort_t* Kb  = (ushort_t*)d_out;
  ushort_t* xbf = (ushort_t*)d_out + NELT;
  char* ws = (char*)d_ws;
  ushort_t* Wbf = (ushort_t*)ws;
  ushort_t* Qb  = (ushort_t*)(ws + 4 * (size_t)CDIM * CDIM * 2);
  ushort_t* Vtb = Qb + NELT;
  ushort_t* AO  = Qb;             // AO aliases Q (per-block exclusive)

  cvt_f32_bf16<<<(int)(NELT / 4 / 256), 256, 0, stream>>>(x, xbf, (int)(NELT / 4));
  cvt_w4<<<dim3(CDIM * CDIM / 4 / 256, 4), 256, 0, stream>>>(Wq, Wk, Wv, Wo, Wbf);

  gemm_qkv<<<dim3(12, (int)(NTOK / 256)), 512, 131072, stream>>>(
      xbf, Wbf, bq, bk, bv, Qb, Kb, Vtb, cosT, sinT);

  attn_kernel<<<dim3(NH, NW * 2, B_SZ), 256, 0, stream>>>(Qb, Kb, Vtb, pm, AO);

  gemm_out<<<dim3(4, (int)(NTOK / 256)), 512, 131072, stream>>>(
      AO, Wbf + 3 * (size_t)CDIM * CDIM, bo, out);
}

// Round 8
// 430.975 us; speedup vs baseline: 1.2504x; 1.2504x over previous
//
#include <hip/hip_runtime.h>
#include <hip/hip_bf16.h>
#include <stdint.h>

#define T_SEQ 8192
#define B_SZ 2
#define CDIM 1024
#define NH 16
#define HDIM 64
#define NW 32

typedef unsigned short ushort_t;
typedef __attribute__((ext_vector_type(8))) short short8;     // 8 bf16 (4 VGPRs) MFMA A/B frag
typedef __attribute__((ext_vector_type(8))) unsigned short us8;
typedef __attribute__((ext_vector_type(4))) unsigned short us4;
typedef __attribute__((ext_vector_type(4))) float f32x4;      // MFMA C/D frag

__device__ __forceinline__ unsigned short f2bf(float f) {
  union { float f; unsigned int u; } c; c.f = f;
  return (unsigned short)((c.u + 0x7FFFu + ((c.u >> 16) & 1u)) >> 16);
}
__device__ __forceinline__ unsigned pk2(float a, float b) {
  unsigned r;
  asm("v_cvt_pk_bf16_f32 %0, %1, %2" : "=v"(r) : "v"(a), "v"(b));
  return r;   // low16 = bf16(a), high16 = bf16(b), RTNE
}
__device__ __forceinline__ void gld16(void* lds, const void* g) {
  __builtin_amdgcn_global_load_lds(
      (const __attribute__((address_space(1))) void*)g,
      (__attribute__((address_space(3))) void*)lds, 16, 0, 0);
}

// ---------------- fp32 -> bf16 conversion (RTNE) ----------------
__global__ __launch_bounds__(256) void cvt_f32_bf16(const float* __restrict__ src,
                                                    ushort_t* __restrict__ dst, int n4)
{
  int i = blockIdx.x * 256 + threadIdx.x;
  if (i < n4) {
    float4 v = ((const float4*)src)[i];
    ushort4 o;
    o.x = f2bf(v.x); o.y = f2bf(v.y); o.z = f2bf(v.z); o.w = f2bf(v.w);
    ((ushort4*)dst)[i] = o;
  }
}

// all 4 weight matrices into one contiguous bf16 buffer (rows 0..4095); grid (1024, 4)
__global__ __launch_bounds__(256) void cvt_w4(const float* __restrict__ w0,
                                              const float* __restrict__ w1,
                                              const float* __restrict__ w2,
                                              const float* __restrict__ w3,
                                              ushort_t* __restrict__ dst)
{
  const float* srcs[4] = {w0, w1, w2, w3};
  const float* s = srcs[blockIdx.y];
  ushort_t* d = dst + (size_t)blockIdx.y * CDIM * CDIM;
  int i = blockIdx.x * 256 + threadIdx.x;
  float4 v = ((const float4*)s)[i];
  ushort4 o;
  o.x = f2bf(v.x); o.y = f2bf(v.y); o.z = f2bf(v.z); o.w = f2bf(v.w);
  ((ushort4*)d)[i] = o;
}

// ---------------- 256x256 BK=64 double-buffered 2-phase GEMM core ----------------
// ROUND-5 EXACT (measured 129.9 us / 793 TF for qkv). Round-6's counted-vmcnt + second
// barrier regressed 7% (graft without per-phase interleave = pure barrier overhead).
// 512 threads = 8 waves (2M x 4N). Per-wave output 128x64 (acc[8][4]).
// LDS (dynamic, 128 KB): As[2][256*64] + Bs[2][256*64], XOR-swizzled 16B blocks.
// Per K-tile: issue next tile's 8 gld16 FIRST, then ds_read+64 MFMA on current buffer,
// then one __syncthreads() (vmcnt0+lgkm0+barrier) — staging hides under compute.
__device__ __forceinline__ void gemm256_core(const ushort_t* __restrict__ A,
                                             const ushort_t* __restrict__ W,
                                             ushort_t* SH,
                                             int m0, int n0, int t, f32x4 acc[8][4])
{
  const int lane = t & 63;
  const int wv = t >> 6;          // 0..7
  const int wr = wv >> 2;         // 0..1  (M half)
  const int wc = wv & 3;          // 0..3  (N quarter)
  const int fr = lane & 15;
  const int quad = lane >> 4;

  ushort_t* As = SH;              // [2][16384]
  ushort_t* Bs = SH + 32768;

  const int sr8 = lane >> 3;                     // 0..7 == staged row & 7
  const int scb = ((lane & 7) ^ sr8) * 8;        // pre-swizzled source col (elems)
  const int srowb = wv * 8 + sr8;                // base staged row (0..63, +p*64)
  const ushort_t* Ag = A + (size_t)(m0 + srowb) * CDIM + scb;
  const ushort_t* Wg = W + (size_t)(n0 + srowb) * CDIM + scb;
  ushort_t* lA = As + srowb * 64 + (lane & 7) * 8;   // linear in lane within a wave
  ushort_t* lB = Bs + srowb * 64 + (lane & 7) * 8;

  // prologue: stage kt=0 into buf 0
#pragma unroll
  for (int p = 0; p < 4; p++) {
    gld16(lA + p * 4096, Ag + (size_t)p * 64 * CDIM);
    gld16(lB + p * 4096, Wg + (size_t)p * 64 * CDIM);
  }
  __syncthreads();

  for (int kt = 0; kt < CDIM / 64; ++kt) {
    const int cur = kt & 1;
    if (kt + 1 < CDIM / 64) {     // issue next tile BEFORE compute (latency hides under MFMA)
      const ushort_t* Agn = Ag + (kt + 1) * 64;
      const ushort_t* Wgn = Wg + (kt + 1) * 64;
      ushort_t* nA = lA + (cur ^ 1) * 16384;
      ushort_t* nB = lB + (cur ^ 1) * 16384;
#pragma unroll
      for (int p = 0; p < 4; p++) {
        gld16(nA + p * 4096, Agn + (size_t)p * 64 * CDIM);
        gld16(nB + p * 4096, Wgn + (size_t)p * 64 * CDIM);
      }
    }
    const ushort_t* Ac = As + cur * 16384;
    const ushort_t* Bc = Bs + cur * 16384;
    short8 b[4][2];
#pragma unroll
    for (int j = 0; j < 4; j++)
#pragma unroll
      for (int ks = 0; ks < 2; ks++)
        b[j][ks] = *(const short8*)&Bc[(wc * 64 + j * 16 + fr) * 64 +
                                       (((ks * 4 + quad) ^ (fr & 7)) * 8)];
    __builtin_amdgcn_s_setprio(1);
#pragma unroll
    for (int i = 0; i < 8; i++) {
      const int ra = (wr * 128 + i * 16 + fr) * 64;
      short8 a0 = *(const short8*)&Ac[ra + ((quad ^ (fr & 7)) * 8)];
      short8 a1 = *(const short8*)&Ac[ra + (((4 + quad) ^ (fr & 7)) * 8)];
#pragma unroll
      for (int j = 0; j < 4; j++)
        acc[i][j] = __builtin_amdgcn_mfma_f32_16x16x32_bf16(a0, b[j][0], acc[i][j], 0, 0, 0);
#pragma unroll
      for (int j = 0; j < 4; j++)
        acc[i][j] = __builtin_amdgcn_mfma_f32_16x16x32_bf16(a1, b[j][1], acc[i][j], 0, 0, 0);
    }
    __builtin_amdgcn_s_setprio(0);
    __syncthreads();              // vmcnt(0)+lgkmcnt(0)+barrier: next tile landed, reads done
  }
}

// XCD-chunked bijective block swizzle (nwg % 8 == 0 for all our grids)
__device__ __forceinline__ void xcd_swz(int& bx, int& by) {
  int gx = gridDim.x, nwg = gx * gridDim.y;
  int lid = bx + gx * by;
  int cpx = nwg >> 3;
  int swz = (lid & 7) * cpx + (lid >> 3);
  bx = swz % gx;
  by = swz / gx;
}

// ---------------- fused QKV projection: N=3072, per-section epilogue ----------------
// grid (12, 64), 512 threads, 128 KB dynamic LDS. sections: bx>>2 -> 0=Q 1=K 2=V.
__global__ __launch_bounds__(512, 1) void gemm_qkv(const ushort_t* __restrict__ A,
                                                   const ushort_t* __restrict__ Wcat,
                                                   const float* __restrict__ bq,
                                                   const float* __restrict__ bk,
                                                   const float* __restrict__ bv,
                                                   ushort_t* __restrict__ Qb,
                                                   ushort_t* __restrict__ Kb,
                                                   ushort_t* __restrict__ Vtb,
                                                   const float* __restrict__ cosT,
                                                   const float* __restrict__ sinT)
{
  extern __shared__ ushort_t SH[];   // 131072 B: K-loop dbuf tiles; epilogue 128x264 retile

  const int t = threadIdx.x;
  const int lane = t & 63;
  const int wv = t >> 6;
  const int wr = wv >> 2;
  const int wc = wv & 3;
  const int fr = lane & 15;
  const int quad = lane >> 4;
  int bx = blockIdx.x, by = blockIdx.y;
  xcd_swz(bx, by);
  const int m0 = by * 256;
  const int n0 = bx * 256;              // row in Wcat (0..3071)
  const int sec = bx >> 2;              // 0=Q 1=K 2=V
  const int nsec0 = (bx & 3) * 256;
  const float* bias = (sec == 0) ? bq : (sec == 1) ? bk : bv;

  f32x4 acc[8][4];
#pragma unroll
  for (int i = 0; i < 8; i++)
#pragma unroll
    for (int j = 0; j < 4; j++) acc[i][j] = (f32x4){0.f, 0.f, 0.f, 0.f};

  gemm256_core(A, Wcat, SH, m0, n0, t, acc);

  if (sec < 2) {
    // RoPE in C-layout regs -> LDS retile (stride 264) in two 128-row passes -> us8 stores
    ushort_t* OutQK = sec ? Kb : Qb;
#pragma unroll
    for (int half = 0; half < 2; ++half) {
      if (wr == half) {
#pragma unroll
        for (int jp = 0; jp < 2; jp++) {
          int d = jp * 16 + fr;               // head-dim lo (0..31)
          int cl = wc * 64 + jp * 16 + fr;    // col in 256-tile
          float bl = bias[nsec0 + cl];
          float bh = bias[nsec0 + cl + 32];
#pragma unroll
          for (int i = 0; i < 8; i++) {
            int rloc = i * 16 + quad * 4;     // row within the 128-row half
#pragma unroll
            for (int r = 0; r < 4; r++) {
              int m = m0 + half * 128 + rloc + r;
              int tt = m & (T_SEQ - 1);
              float c = cosT[tt * HDIM + d];
              float sn = sinT[tt * HDIM + d];
              float lo = acc[i][jp][r] + bl;
              float hi = acc[i][jp + 2][r] + bh;
              SH[(rloc + r) * 264 + cl] = f2bf(lo * c - hi * sn);
              SH[(rloc + r) * 264 + cl + 32] = f2bf(hi * c + lo * sn);
            }
          }
        }
      }
      __syncthreads();
      const int rr0 = t >> 5;                 // 0..15
      const int c8 = (t & 31) * 8;            // 0..248
      size_t gbase = (size_t)(m0 + half * 128) * CDIM + nsec0 + c8;
#pragma unroll
      for (int pp = 0; pp < 8; pp++) {
        int rr = pp * 16 + rr0;
        *(us8*)&OutQK[gbase + (size_t)rr * CDIM] = *(const us8*)&SH[rr * 264 + c8];
      }
      __syncthreads();
    }
  } else {
    // V -> Vt[b][ch][tok], 4 consecutive tokens per 8B store
#pragma unroll
    for (int j = 0; j < 4; j++) {
      int ch = nsec0 + wc * 64 + j * 16 + fr;
      float bvv = bias[ch];
#pragma unroll
      for (int i = 0; i < 8; i++) {
        int m = m0 + wr * 128 + i * 16 + quad * 4;
        int bb = m >> 13;
        int tq = m & (T_SEQ - 1);
        us4 pk;
#pragma unroll
        for (int r = 0; r < 4; r++) pk[r] = f2bf(acc[i][j][r] + bvv);
        *(us4*)&Vtb[((size_t)bb * CDIM + ch) * T_SEQ + tq] = pk;
      }
    }
  }
}

// ---------------- output projection: bf16 in, fp32 out; grid (4, 64) ----------------
__global__ __launch_bounds__(512, 1) void gemm_out(const ushort_t* __restrict__ A,
                                                   const ushort_t* __restrict__ W,
                                                   const float* __restrict__ bias,
                                                   float* __restrict__ Out)
{
  extern __shared__ ushort_t SH[];

  const int t = threadIdx.x;
  const int lane = t & 63;
  const int wv = t >> 6;
  const int wr = wv >> 2;
  const int wc = wv & 3;
  const int fr = lane & 15;
  const int quad = lane >> 4;
  int bx = blockIdx.x, by = blockIdx.y;
  xcd_swz(bx, by);
  const int m0 = by * 256;
  const int n0 = bx * 256;

  f32x4 acc[8][4];
#pragma unroll
  for (int i = 0; i < 8; i++)
#pragma unroll
    for (int j = 0; j < 4; j++) acc[i][j] = (f32x4){0.f, 0.f, 0.f, 0.f};

  gemm256_core(A, W, SH, m0, n0, t, acc);

#pragma unroll
  for (int j = 0; j < 4; j++) {
    int n = n0 + wc * 64 + j * 16 + fr;
    float bvv = bias[n];
#pragma unroll
    for (int i = 0; i < 8; i++) {
      int m = m0 + wr * 128 + i * 16 + quad * 4;
#pragma unroll
      for (int r = 0; r < 4; r++)
        Out[(size_t)(m + r) * CDIM + n] = acc[i][j][r] + bvv;
    }
  }
}

// ---------------- windowed attention (round-1 body: known-good ~120 us) ----------------
// ONE change vs round-5: grid is (NH*2, NW, B) with blockIdx.x = qh + 2*h, so the qh pair
// (which reads byte-identical K/V slices) is ADJACENT in dispatch order (distance 1 instead
// of 16) -> follower's K/V staging hits L2 instead of L3/HBM. Kernel body untouched
// (r2/r7: any change to attn's residency/timing pattern collapses this L2 reuse).
__global__ __launch_bounds__(256, 4) void attn_kernel(const ushort_t* __restrict__ Q,
                                                      const ushort_t* __restrict__ Kg,
                                                      const ushort_t* __restrict__ Vt,
                                                      const int* __restrict__ mask,
                                                      ushort_t* __restrict__ AO)
{
  __shared__ ushort_t Ks[64 * 72];            //  9216 B  [key][dim]
  __shared__ ushort_t Vts[64 * 72];           //  9216 B  [dim][key]
  __shared__ unsigned int PsW[4 * 32 * 32];   // 16384 B  per-wave 32 rows x 32 words, XOR-swz
  __shared__ float attf[512];                 //  2048 B  additive key bias (0 / -1e38)

  const int t = threadIdx.x;
  const int lane = t & 63;
  const int wv = t >> 6;
  const int h = blockIdx.x >> 1;
  const int qh = blockIdx.x & 1;
  const int w = blockIdx.y;
  const int b = blockIdx.z;
  const int fr = lane & 15;
  const int quad = lane >> 4;

  {
    int p0 = w * 256 + t - 128;
    bool a0 = (p0 < 0 || p0 >= T_SEQ) ? true : (mask[b * T_SEQ + p0] == 0);
    int p1 = p0 + 256;
    bool a1 = (p1 < 0 || p1 >= T_SEQ) ? true : (mask[b * T_SEQ + p1] == 0);
    int all1 = __syncthreads_and((int)(a0 && a1));
    attf[t] = a0 ? 0.f : -1.0e38f;
    attf[t + 256] = a1 ? 0.f : -1.0e38f;
    if (all1 && t == 0) attf[0] = -1.0e38f;   // reference quirk: fully-attendable -> mask key 0
  }

  // Q -> registers (B-frag of QK^T): lane holds Q[mt*16+fr][ks*32+quad*8 ..+7]
  short8 qf[2][2];
  {
    const ushort_t* qp = Q + ((size_t)b * T_SEQ + w * 256 + qh * 128 + wv * 32 + fr) * CDIM
                           + h * HDIM + quad * 8;
#pragma unroll
    for (int mt = 0; mt < 2; mt++)
#pragma unroll
      for (int ks = 0; ks < 2; ks++)
        qf[mt][ks] = *(const short8*)&qp[(size_t)mt * 16 * CDIM + ks * 32];
  }

  const int srow = t >> 3;                    // 0..31
  const int sc8 = (t & 7) * 8;
  const ushort_t* kgb = Kg + (size_t)b * T_SEQ * CDIM + h * HDIM + sc8;
  const ushort_t* vt_base = Vt + ((size_t)b * CDIM + h * HDIM) * T_SEQ;
  const float SCL = 0.18033688011112042f;     // 0.125 * log2(e)

  unsigned int* pw = &PsW[wv * 1024];
  const int swz = (fr & 7) << 2;
  const int rbase = quad << 2;

  float m_run[2], l_run[2];
  f32x4 o[2][4];
#pragma unroll
  for (int mt = 0; mt < 2; mt++) { m_run[mt] = -3.0e38f; l_run[mt] = 0.f; }
#pragma unroll
  for (int mt = 0; mt < 2; mt++)
#pragma unroll
    for (int nt = 0; nt < 4; nt++) o[mt][nt] = (f32x4){0.f, 0.f, 0.f, 0.f};

  for (int kc = 0; kc < 8; kc++) {
    __syncthreads();
    {
#pragma unroll
      for (int p = 0; p < 2; p++) {
        int jj = p * 32 + srow;
        int pos = w * 256 + kc * 64 + jj - 128;
        us8 kval = (us8)(0);
        if (pos >= 0 && pos < T_SEQ) kval = *(const us8*)&kgb[(size_t)pos * CDIM];
        *(us8*)&Ks[jj * 72 + sc8] = kval;
      }
      int pos0 = w * 256 + kc * 64 - 128 + sc8;
      bool inr = (pos0 >= 0) && (pos0 < T_SEQ);
#pragma unroll
      for (int p = 0; p < 2; p++) {
        int d = p * 32 + srow;
        us8 vv = (us8)(0);
        if (inr) vv = *(const us8*)&vt_base[(size_t)d * T_SEQ + pos0];
        *(us8*)&Vts[d * 72 + sc8] = vv;
      }
    }
    __syncthreads();

    // S^T = K·Q^T : lane holds key = nt*16+quad*4+r, q-row = mt*16+fr
    short8 kf[4][2];
#pragma unroll
    for (int nt = 0; nt < 4; nt++)
#pragma unroll
      for (int ks = 0; ks < 2; ks++)
        kf[nt][ks] = *(const short8*)&Ks[(nt * 16 + fr) * 72 + ks * 32 + quad * 8];

    f32x4 st[2][4];
    __builtin_amdgcn_s_setprio(1);
#pragma unroll
    for (int mt = 0; mt < 2; mt++)
#pragma unroll
      for (int nt = 0; nt < 4; nt++) {
        f32x4 a = (f32x4){0.f, 0.f, 0.f, 0.f};
        a = __builtin_amdgcn_mfma_f32_16x16x32_bf16(kf[nt][0], qf[mt][0], a, 0, 0, 0);
        a = __builtin_amdgcn_mfma_f32_16x16x32_bf16(kf[nt][1], qf[mt][1], a, 0, 0, 0);
        st[mt][nt] = a;
      }
    __builtin_amdgcn_s_setprio(0);

    // scale + mask fused (exp2 domain); kb[nt][r] is key 16nt+4*quad+r
    f32x4 kb[4];
#pragma unroll
    for (int nt = 0; nt < 4; nt++)
      kb[nt] = *(const f32x4*)&attf[kc * 64 + nt * 16 + quad * 4];
#pragma unroll
    for (int mt = 0; mt < 2; mt++)
#pragma unroll
      for (int nt = 0; nt < 4; nt++)
#pragma unroll
        for (int r = 0; r < 4; r++)
          st[mt][nt][r] = __builtin_fmaf(st[mt][nt][r], SCL, kb[nt][r]);

    // lane-local online softmax (rows mt*16+fr), defer-max THR=8
#pragma unroll
    for (int mt = 0; mt < 2; mt++) {
      float t0 = fmaxf(fmaxf(st[mt][0][0], st[mt][0][1]), fmaxf(st[mt][0][2], st[mt][0][3]));
      float t1 = fmaxf(fmaxf(st[mt][1][0], st[mt][1][1]), fmaxf(st[mt][1][2], st[mt][1][3]));
      float t2 = fmaxf(fmaxf(st[mt][2][0], st[mt][2][1]), fmaxf(st[mt][2][2], st[mt][2][3]));
      float t3 = fmaxf(fmaxf(st[mt][3][0], st[mt][3][1]), fmaxf(st[mt][3][2], st[mt][3][3]));
      float mx = fmaxf(fmaxf(t0, t1), fmaxf(t2, t3));
      mx = fmaxf(mx, __shfl_xor(mx, 16, 64));
      mx = fmaxf(mx, __shfl_xor(mx, 32, 64));
      if (!__all(mx <= m_run[mt] + 8.f)) {
        float mnew = fmaxf(m_run[mt], mx);
        float alpha = __builtin_amdgcn_exp2f(m_run[mt] - mnew);
        m_run[mt] = mnew;
        l_run[mt] *= alpha;
        float af[4];
#pragma unroll
        for (int r = 0; r < 4; r++) af[r] = __shfl(alpha, rbase + r, 64);
#pragma unroll
        for (int nt = 0; nt < 4; nt++)
#pragma unroll
          for (int r = 0; r < 4; r++) o[mt][nt][r] *= af[r];
      }
      float rs = 0.f;
#pragma unroll
      for (int nt = 0; nt < 4; nt++)
#pragma unroll
        for (int r = 0; r < 4; r++) {
          float p = __builtin_amdgcn_exp2f(st[mt][nt][r] - m_run[mt]);
          st[mt][nt][r] = p;
          rs += p;
        }
      rs += __shfl_xor(rs, 16, 64);
      rs += __shfl_xor(rs, 32, 64);
      l_run[mt] += rs;

      // pack P row -> per-wave exchange buffer (word w=8nt+2q+h holds keys 2w,2w+1)
      unsigned int* pr = pw + ((mt * 16 + fr) << 5);
#pragma unroll
      for (int nt = 0; nt < 4; nt++)
#pragma unroll
        for (int hh = 0; hh < 2; hh++)
          pr[(((nt << 3) + (quad << 1) + hh)) ^ swz] =
              pk2(st[mt][nt][2 * hh], st[mt][nt][2 * hh + 1]);
    }

    // PV: A = P-frag (keys ks*32+quad*8 ..+7 of row mt*16+fr), B = V-frag from Vts
    short8 vf[4][2];
#pragma unroll
    for (int nt = 0; nt < 4; nt++)
#pragma unroll
      for (int ks = 0; ks < 2; ks++)
        vf[nt][ks] = *(const short8*)&Vts[(nt * 16 + fr) * 72 + ks * 32 + quad * 8];

    __builtin_amdgcn_s_setprio(1);
#pragma unroll
    for (int mt = 0; mt < 2; mt++) {
      const unsigned int* pr = pw + ((mt * 16 + fr) << 5);
      short8 pf[2];
#pragma unroll
      for (int ks = 0; ks < 2; ks++)
        pf[ks] = *(const short8*)&pr[((ks << 4) + (quad << 2)) ^ swz];
#pragma unroll
      for (int nt = 0; nt < 4; nt++) {
        o[mt][nt] = __builtin_amdgcn_mfma_f32_16x16x32_bf16(pf[0], vf[nt][0], o[mt][nt], 0, 0, 0);
        o[mt][nt] = __builtin_amdgcn_mfma_f32_16x16x32_bf16(pf[1], vf[nt][1], o[mt][nt], 0, 0, 0);
      }
    }
    __builtin_amdgcn_s_setprio(0);
  }

  // epilogue: o rows = wv*32 + mt*16 + quad*4 + r; pull 1/l from the lane owning that row
  size_t obase = ((size_t)b * T_SEQ + w * 256 + qh * 128 + wv * 32) * CDIM + h * HDIM;
#pragma unroll
  for (int mt = 0; mt < 2; mt++)
#pragma unroll
    for (int r = 0; r < 4; r++) {
      float lv = __shfl(l_run[mt], rbase + r, 64);
      float iv = 1.0f / fmaxf(lv, 1e-30f);
      int row = mt * 16 + quad * 4 + r;
#pragma unroll
      for (int nt = 0; nt < 4; nt++)
        AO[obase + (size_t)row * CDIM + nt * 16 + fr] = f2bf(o[mt][nt][r] * iv);
    }
}

extern "C" void kernel_launch(void* const* d_in, const int* in_sizes, int n_in,
                              void* d_out, int out_size, void* d_ws, size_t ws_size,
                              hipStream_t stream)
{
  const float* x    = (const float*)d_in[0];
  const int*   pm   = (const int*)d_in[1];
  const float* cosT = (const float*)d_in[2];
  const float* sinT = (const float*)d_in[3];
  const float* Wq   = (const float*)d_in[4];
  const float* bq   = (const float*)d_in[5];
  const float* Wk   = (const float*)d_in[6];
  const float* bk   = (const float*)d_in[7];
  const float* Wv   = (const float*)d_in[8];
  const float* bv   = (const float*)d_in[9];
  const float* Wo   = (const float*)d_in[10];
  const float* bo   = (const float*)d_in[11];
  float* out = (float*)d_out;

  static bool attr_done = false;
  if (!attr_done) {
    hipFuncSetAttribute(reinterpret_cast<const void*>(gemm_qkv),
                        hipFuncAttributeMaxDynamicSharedMemorySize, 131072);
    hipFuncSetAttribute(reinterpret_cast<const void*>(gemm_out),
                        hipFuncAttributeMaxDynamicSharedMemorySize, 131072);
    attr_done = true;
  }

  // scratch layout:
  //   d_out lower half : K (bf16)       — dead before final GEMM overwrites d_out
  //   d_out upper half : x_bf (bf16)    — dead after QKV projection
  //   ws: Wcat bf16 [Wq;Wk;Wv;Wo] (8 MB) + Q (33.5) + Vt (33.5, [b][ch][tok])
  const size_t NTOK = (size_t)B_SZ * T_SEQ;
  const size_t NELT = NTOK * CDIM;
  ushort_t* Kb  = (ushort_t*)d_out;
  ushort_t* xbf = (ushort_t*)d_out + NELT;
  char* ws = (char*)d_ws;
  ushort_t* Wbf = (ushort_t*)ws;
  ushort_t* Qb  = (ushort_t*)(ws + 4 * (size_t)CDIM * CDIM * 2);
  ushort_t* Vtb = Qb + NELT;
  ushort_t* AO  = Qb;             // AO aliases Q (per-block exclusive)

  cvt_f32_bf16<<<(int)(NELT / 4 / 256), 256, 0, stream>>>(x, xbf, (int)(NELT / 4));
  cvt_w4<<<dim3(CDIM * CDIM / 4 / 256, 4), 256, 0, stream>>>(Wq, Wk, Wv, Wo, Wbf);

  gemm_qkv<<<dim3(12, (int)(NTOK / 256)), 512, 131072, stream>>>(
      xbf, Wbf, bq, bk, bv, Qb, Kb, Vtb, cosT, sinT);

  attn_kernel<<<dim3(NH * 2, NW, B_SZ), 256, 0, stream>>>(Qb, Kb, Vtb, pm, AO);

  gemm_out<<<dim3(4, (int)(NTOK / 256)), 512, 131072, stream>>>(
      AO, Wbf + 3 * (size_t)CDIM * CDIM, bo, out);
}

// Round 9
// 422.824 us; speedup vs baseline: 1.2745x; 1.0193x over previous
//
#include <hip/hip_runtime.h>
#include <hip/hip_bf16.h>
#include <stdint.h>

#define T_SEQ 8192
#define B_SZ 2
#define CDIM 1024
#define NH 16
#define HDIM 64
#define NW 32

typedef unsigned short ushort_t;
typedef __attribute__((ext_vector_type(8))) short short8;     // 8 bf16 (4 VGPRs) MFMA A/B frag
typedef __attribute__((ext_vector_type(8))) unsigned short us8;
typedef __attribute__((ext_vector_type(4))) unsigned short us4;
typedef __attribute__((ext_vector_type(4))) float f32x4;      // MFMA C/D frag

__device__ __forceinline__ unsigned short f2bf(float f) {
  union { float f; unsigned int u; } c; c.f = f;
  return (unsigned short)((c.u + 0x7FFFu + ((c.u >> 16) & 1u)) >> 16);
}
__device__ __forceinline__ unsigned pk2(float a, float b) {
  unsigned r;
  asm("v_cvt_pk_bf16_f32 %0, %1, %2" : "=v"(r) : "v"(a), "v"(b));
  return r;   // low16 = bf16(a), high16 = bf16(b), RTNE
}
__device__ __forceinline__ void gld16(void* lds, const void* g) {
  __builtin_amdgcn_global_load_lds(
      (const __attribute__((address_space(1))) void*)g,
      (__attribute__((address_space(3))) void*)lds, 16, 0, 0);
}

// ---------------- fp32 -> bf16 conversion (RTNE) ----------------
__global__ __launch_bounds__(256) void cvt_f32_bf16(const float* __restrict__ src,
                                                    ushort_t* __restrict__ dst, int n4)
{
  int i = blockIdx.x * 256 + threadIdx.x;
  if (i < n4) {
    float4 v = ((const float4*)src)[i];
    ushort4 o;
    o.x = f2bf(v.x); o.y = f2bf(v.y); o.z = f2bf(v.z); o.w = f2bf(v.w);
    ((ushort4*)dst)[i] = o;
  }
}

// all 4 weight matrices into one contiguous bf16 buffer (rows 0..4095); grid (1024, 4)
__global__ __launch_bounds__(256) void cvt_w4(const float* __restrict__ w0,
                                              const float* __restrict__ w1,
                                              const float* __restrict__ w2,
                                              const float* __restrict__ w3,
                                              ushort_t* __restrict__ dst)
{
  const float* srcs[4] = {w0, w1, w2, w3};
  const float* s = srcs[blockIdx.y];
  ushort_t* d = dst + (size_t)blockIdx.y * CDIM * CDIM;
  int i = blockIdx.x * 256 + threadIdx.x;
  float4 v = ((const float4*)s)[i];
  ushort4 o;
  o.x = f2bf(v.x); o.y = f2bf(v.y); o.z = f2bf(v.z); o.w = f2bf(v.w);
  ((ushort4*)d)[i] = o;
}

// ---------------- 256x256 BK=32 double-buffered 2-phase GEMM core ----------------
// Same sync structure as the round-5 template (issue next-tile gld16 FIRST, compute, ONE
// __syncthreads per tile); BK 64->32 halves LDS to 64 KB -> 2 blocks/CU (launch_bounds(512,2))
// so the other block's MFMA covers the stage stall that a single block exposes (m132 inverse).
// 512 threads = 8 waves (2M x 4N). Per-wave output 128x64 (acc[8][4]).
// LDS: As[2][256*32] + Bs[2][256*32] bf16. Rows are 64 B; read swizzle blk = quad^(fr&3)
// gives the uniform 8-pass minimum for ds_read_b128 (conflict-free); staging source is
// pre-swizzled to match, LDS dest stays linear for global_load_lds (both-sides rule).
__device__ __forceinline__ void gemm256_core(const ushort_t* __restrict__ A,
                                             const ushort_t* __restrict__ W,
                                             ushort_t* SH,
                                             int m0, int n0, int t, f32x4 acc[8][4])
{
  const int lane = t & 63;
  const int wv = t >> 6;          // 0..7
  const int wr = wv >> 2;         // 0..1  (M half)
  const int wc = wv & 3;          // 0..3  (N quarter)
  const int fr = lane & 15;
  const int quad = lane >> 4;

  ushort_t* As = SH;              // [2][8192] elems
  ushort_t* Bs = SH + 16384;

  // staging: wave covers 16 rows x 4 16B-blocks per issue; 2 issues (rows +128) per matrix
  const int r0 = wv * 16 + (lane >> 2);          // staged row (issue p adds p*128; 128%4==0)
  const int scb = ((lane & 3) ^ (r0 & 3)) * 8;   // pre-swizzled source col (elems)
  const ushort_t* Ag = A + (size_t)(m0 + r0) * CDIM + scb;
  const ushort_t* Wg = W + (size_t)(n0 + r0) * CDIM + scb;
  ushort_t* lA = As + r0 * 32 + (lane & 3) * 8;  // = wave base + lane*16B (linear) ✓
  ushort_t* lB = Bs + r0 * 32 + (lane & 3) * 8;

  // prologue: stage kt=0 into buf 0
#pragma unroll
  for (int p = 0; p < 2; p++) {
    gld16(lA + p * 4096, Ag + (size_t)p * 128 * CDIM);
    gld16(lB + p * 4096, Wg + (size_t)p * 128 * CDIM);
  }
  __syncthreads();

  const int rblk = (quad ^ (fr & 3)) * 8;        // read-side swizzled block (elems)

  for (int kt = 0; kt < CDIM / 32; ++kt) {
    const int cur = kt & 1;
    if (kt + 1 < CDIM / 32) {     // issue next tile BEFORE compute (latency hides under MFMA)
      const int kc = (kt + 1) * 32;
      ushort_t* nA = lA + (cur ^ 1) * 8192;
      ushort_t* nB = lB + (cur ^ 1) * 8192;
#pragma unroll
      for (int p = 0; p < 2; p++) {
        gld16(nA + p * 4096, Ag + (size_t)p * 128 * CDIM + kc);
        gld16(nB + p * 4096, Wg + (size_t)p * 128 * CDIM + kc);
      }
    }
    const ushort_t* Ac = As + cur * 8192;
    const ushort_t* Bc = Bs + cur * 8192;
    short8 b[4];
#pragma unroll
    for (int j = 0; j < 4; j++)
      b[j] = *(const short8*)&Bc[(wc * 64 + j * 16 + fr) * 32 + rblk];
    __builtin_amdgcn_s_setprio(1);
#pragma unroll
    for (int i = 0; i < 8; i++) {
      short8 a = *(const short8*)&Ac[(wr * 128 + i * 16 + fr) * 32 + rblk];
#pragma unroll
      for (int j = 0; j < 4; j++)
        acc[i][j] = __builtin_amdgcn_mfma_f32_16x16x32_bf16(a, b[j], acc[i][j], 0, 0, 0);
    }
    __builtin_amdgcn_s_setprio(0);
    __syncthreads();              // vmcnt(0)+lgkmcnt(0)+barrier: next tile landed, reads done
  }
}

// XCD-chunked bijective block swizzle (nwg % 8 == 0 for all our grids)
__device__ __forceinline__ void xcd_swz(int& bx, int& by) {
  int gx = gridDim.x, nwg = gx * gridDim.y;
  int lid = bx + gx * by;
  int cpx = nwg >> 3;
  int swz = (lid & 7) * cpx + (lid >> 3);
  bx = swz % gx;
  by = swz / gx;
}

// ---------------- fused QKV projection: N=3072, per-section epilogue ----------------
// grid (12, 64), 512 threads, 66 KB dynamic LDS (64 KB K-loop, 67584 B epilogue retile).
__global__ __launch_bounds__(512, 2) void gemm_qkv(const ushort_t* __restrict__ A,
                                                   const ushort_t* __restrict__ Wcat,
                                                   const float* __restrict__ bq,
                                                   const float* __restrict__ bk,
                                                   const float* __restrict__ bv,
                                                   ushort_t* __restrict__ Qb,
                                                   ushort_t* __restrict__ Kb,
                                                   ushort_t* __restrict__ Vtb,
                                                   const float* __restrict__ cosT,
                                                   const float* __restrict__ sinT)
{
  extern __shared__ ushort_t SH[];   // 67584 B

  const int t = threadIdx.x;
  const int lane = t & 63;
  const int wv = t >> 6;
  const int wr = wv >> 2;
  const int wc = wv & 3;
  const int fr = lane & 15;
  const int quad = lane >> 4;
  int bx = blockIdx.x, by = blockIdx.y;
  xcd_swz(bx, by);
  const int m0 = by * 256;
  const int n0 = bx * 256;              // row in Wcat (0..3071)
  const int sec = bx >> 2;              // 0=Q 1=K 2=V
  const int nsec0 = (bx & 3) * 256;
  const float* bias = (sec == 0) ? bq : (sec == 1) ? bk : bv;

  f32x4 acc[8][4];
#pragma unroll
  for (int i = 0; i < 8; i++)
#pragma unroll
    for (int j = 0; j < 4; j++) acc[i][j] = (f32x4){0.f, 0.f, 0.f, 0.f};

  gemm256_core(A, Wcat, SH, m0, n0, t, acc);

  if (sec < 2) {
    // RoPE in C-layout regs -> LDS retile (stride 264) in two 128-row passes -> us8 stores
    ushort_t* OutQK = sec ? Kb : Qb;
#pragma unroll
    for (int half = 0; half < 2; ++half) {
      if (wr == half) {
#pragma unroll
        for (int jp = 0; jp < 2; jp++) {
          int d = jp * 16 + fr;               // head-dim lo (0..31)
          int cl = wc * 64 + jp * 16 + fr;    // col in 256-tile
          float bl = bias[nsec0 + cl];
          float bh = bias[nsec0 + cl + 32];
#pragma unroll
          for (int i = 0; i < 8; i++) {
            int rloc = i * 16 + quad * 4;     // row within the 128-row half
#pragma unroll
            for (int r = 0; r < 4; r++) {
              int m = m0 + half * 128 + rloc + r;
              int tt = m & (T_SEQ - 1);
              float c = cosT[tt * HDIM + d];
              float sn = sinT[tt * HDIM + d];
              float lo = acc[i][jp][r] + bl;
              float hi = acc[i][jp + 2][r] + bh;
              SH[(rloc + r) * 264 + cl] = f2bf(lo * c - hi * sn);
              SH[(rloc + r) * 264 + cl + 32] = f2bf(hi * c + lo * sn);
            }
          }
        }
      }
      __syncthreads();
      const int rr0 = t >> 5;                 // 0..15
      const int c8 = (t & 31) * 8;            // 0..248
      size_t gbase = (size_t)(m0 + half * 128) * CDIM + nsec0 + c8;
#pragma unroll
      for (int pp = 0; pp < 8; pp++) {
        int rr = pp * 16 + rr0;
        *(us8*)&OutQK[gbase + (size_t)rr * CDIM] = *(const us8*)&SH[rr * 264 + c8];
      }
      __syncthreads();
    }
  } else {
    // V -> Vt[b][ch][tok], 4 consecutive tokens per 8B store
#pragma unroll
    for (int j = 0; j < 4; j++) {
      int ch = nsec0 + wc * 64 + j * 16 + fr;
      float bvv = bias[ch];
#pragma unroll
      for (int i = 0; i < 8; i++) {
        int m = m0 + wr * 128 + i * 16 + quad * 4;
        int bb = m >> 13;
        int tq = m & (T_SEQ - 1);
        us4 pk;
#pragma unroll
        for (int r = 0; r < 4; r++) pk[r] = f2bf(acc[i][j][r] + bvv);
        *(us4*)&Vtb[((size_t)bb * CDIM + ch) * T_SEQ + tq] = pk;
      }
    }
  }
}

// ---------------- output projection: bf16 in, fp32 out; grid (4, 64) ----------------
__global__ __launch_bounds__(512, 2) void gemm_out(const ushort_t* __restrict__ A,
                                                   const ushort_t* __restrict__ W,
                                                   const float* __restrict__ bias,
                                                   float* __restrict__ Out)
{
  extern __shared__ ushort_t SH[];   // 65536 B

  const int t = threadIdx.x;
  const int lane = t & 63;
  const int wv = t >> 6;
  const int wr = wv >> 2;
  const int wc = wv & 3;
  const int fr = lane & 15;
  const int quad = lane >> 4;
  int bx = blockIdx.x, by = blockIdx.y;
  xcd_swz(bx, by);
  const int m0 = by * 256;
  const int n0 = bx * 256;

  f32x4 acc[8][4];
#pragma unroll
  for (int i = 0; i < 8; i++)
#pragma unroll
    for (int j = 0; j < 4; j++) acc[i][j] = (f32x4){0.f, 0.f, 0.f, 0.f};

  gemm256_core(A, W, SH, m0, n0, t, acc);

#pragma unroll
  for (int j = 0; j < 4; j++) {
    int n = n0 + wc * 64 + j * 16 + fr;
    float bvv = bias[n];
#pragma unroll
    for (int i = 0; i < 8; i++) {
      int m = m0 + wr * 128 + i * 16 + quad * 4;
#pragma unroll
      for (int r = 0; r < 4; r++)
        Out[(size_t)(m + r) * CDIM + n] = acc[i][j][r] + bvv;
    }
  }
}

// ---------------- windowed attention (round-5 config EXACT — frozen) ----------------
// r2/r7/r8 all showed: any change to attn's grid order, residency, or liveness pattern
// collapses the inter-block L2 reuse of the shared K/V streams (FETCH 2-5x). Do not touch.
__global__ __launch_bounds__(256, 4) void attn_kernel(const ushort_t* __restrict__ Q,
                                                      const ushort_t* __restrict__ Kg,
                                                      const ushort_t* __restrict__ Vt,
                                                      const int* __restrict__ mask,
                                                      ushort_t* __restrict__ AO)
{
  __shared__ ushort_t Ks[64 * 72];            //  9216 B  [key][dim]
  __shared__ ushort_t Vts[64 * 72];           //  9216 B  [dim][key]
  __shared__ unsigned int PsW[4 * 32 * 32];   // 16384 B  per-wave 32 rows x 32 words, XOR-swz
  __shared__ float attf[512];                 //  2048 B  additive key bias (0 / -1e38)

  const int t = threadIdx.x;
  const int lane = t & 63;
  const int wv = t >> 6;
  const int h = blockIdx.x;
  const int w = blockIdx.y >> 1;
  const int qh = blockIdx.y & 1;
  const int b = blockIdx.z;
  const int fr = lane & 15;
  const int quad = lane >> 4;

  {
    int p0 = w * 256 + t - 128;
    bool a0 = (p0 < 0 || p0 >= T_SEQ) ? true : (mask[b * T_SEQ + p0] == 0);
    int p1 = p0 + 256;
    bool a1 = (p1 < 0 || p1 >= T_SEQ) ? true : (mask[b * T_SEQ + p1] == 0);
    int all1 = __syncthreads_and((int)(a0 && a1));
    attf[t] = a0 ? 0.f : -1.0e38f;
    attf[t + 256] = a1 ? 0.f : -1.0e38f;
    if (all1 && t == 0) attf[0] = -1.0e38f;   // reference quirk: fully-attendable -> mask key 0
  }

  // Q -> registers (B-frag of QK^T): lane holds Q[mt*16+fr][ks*32+quad*8 ..+7]
  short8 qf[2][2];
  {
    const ushort_t* qp = Q + ((size_t)b * T_SEQ + w * 256 + qh * 128 + wv * 32 + fr) * CDIM
                           + h * HDIM + quad * 8;
#pragma unroll
    for (int mt = 0; mt < 2; mt++)
#pragma unroll
      for (int ks = 0; ks < 2; ks++)
        qf[mt][ks] = *(const short8*)&qp[(size_t)mt * 16 * CDIM + ks * 32];
  }

  const int srow = t >> 3;                    // 0..31
  const int sc8 = (t & 7) * 8;
  const ushort_t* kgb = Kg + (size_t)b * T_SEQ * CDIM + h * HDIM + sc8;
  const ushort_t* vt_base = Vt + ((size_t)b * CDIM + h * HDIM) * T_SEQ;
  const float SCL = 0.18033688011112042f;     // 0.125 * log2(e)

  unsigned int* pw = &PsW[wv * 1024];
  const int swz = (fr & 7) << 2;
  const int rbase = quad << 2;

  float m_run[2], l_run[2];
  f32x4 o[2][4];
#pragma unroll
  for (int mt = 0; mt < 2; mt++) { m_run[mt] = -3.0e38f; l_run[mt] = 0.f; }
#pragma unroll
  for (int mt = 0; mt < 2; mt++)
#pragma unroll
    for (int nt = 0; nt < 4; nt++) o[mt][nt] = (f32x4){0.f, 0.f, 0.f, 0.f};

  for (int kc = 0; kc < 8; kc++) {
    __syncthreads();
    {
#pragma unroll
      for (int p = 0; p < 2; p++) {
        int jj = p * 32 + srow;
        int pos = w * 256 + kc * 64 + jj - 128;
        us8 kval = (us8)(0);
        if (pos >= 0 && pos < T_SEQ) kval = *(const us8*)&kgb[(size_t)pos * CDIM];
        *(us8*)&Ks[jj * 72 + sc8] = kval;
      }
      int pos0 = w * 256 + kc * 64 - 128 + sc8;
      bool inr = (pos0 >= 0) && (pos0 < T_SEQ);
#pragma unroll
      for (int p = 0; p < 2; p++) {
        int d = p * 32 + srow;
        us8 vv = (us8)(0);
        if (inr) vv = *(const us8*)&vt_base[(size_t)d * T_SEQ + pos0];
        *(us8*)&Vts[d * 72 + sc8] = vv;
      }
    }
    __syncthreads();

    // S^T = K·Q^T : lane holds key = nt*16+quad*4+r, q-row = mt*16+fr
    short8 kf[4][2];
#pragma unroll
    for (int nt = 0; nt < 4; nt++)
#pragma unroll
      for (int ks = 0; ks < 2; ks++)
        kf[nt][ks] = *(const short8*)&Ks[(nt * 16 + fr) * 72 + ks * 32 + quad * 8];

    f32x4 st[2][4];
    __builtin_amdgcn_s_setprio(1);
#pragma unroll
    for (int mt = 0; mt < 2; mt++)
#pragma unroll
      for (int nt = 0; nt < 4; nt++) {
        f32x4 a = (f32x4){0.f, 0.f, 0.f, 0.f};
        a = __builtin_amdgcn_mfma_f32_16x16x32_bf16(kf[nt][0], qf[mt][0], a, 0, 0, 0);
        a = __builtin_amdgcn_mfma_f32_16x16x32_bf16(kf[nt][1], qf[mt][1], a, 0, 0, 0);
        st[mt][nt] = a;
      }
    __builtin_amdgcn_s_setprio(0);

    // scale + mask fused (exp2 domain); kb[nt][r] is key 16nt+4*quad+r
    f32x4 kb[4];
#pragma unroll
    for (int nt = 0; nt < 4; nt++)
      kb[nt] = *(const f32x4*)&attf[kc * 64 + nt * 16 + quad * 4];
#pragma unroll
    for (int mt = 0; mt < 2; mt++)
#pragma unroll
      for (int nt = 0; nt < 4; nt++)
#pragma unroll
        for (int r = 0; r < 4; r++)
          st[mt][nt][r] = __builtin_fmaf(st[mt][nt][r], SCL, kb[nt][r]);

    // lane-local online softmax (rows mt*16+fr), defer-max THR=8
#pragma unroll
    for (int mt = 0; mt < 2; mt++) {
      float t0 = fmaxf(fmaxf(st[mt][0][0], st[mt][0][1]), fmaxf(st[mt][0][2], st[mt][0][3]));
      float t1 = fmaxf(fmaxf(st[mt][1][0], st[mt][1][1]), fmaxf(st[mt][1][2], st[mt][1][3]));
      float t2 = fmaxf(fmaxf(st[mt][2][0], st[mt][2][1]), fmaxf(st[mt][2][2], st[mt][2][3]));
      float t3 = fmaxf(fmaxf(st[mt][3][0], st[mt][3][1]), fmaxf(st[mt][3][2], st[mt][3][3]));
      float mx = fmaxf(fmaxf(t0, t1), fmaxf(t2, t3));
      mx = fmaxf(mx, __shfl_xor(mx, 16, 64));
      mx = fmaxf(mx, __shfl_xor(mx, 32, 64));
      if (!__all(mx <= m_run[mt] + 8.f)) {
        float mnew = fmaxf(m_run[mt], mx);
        float alpha = __builtin_amdgcn_exp2f(m_run[mt] - mnew);
        m_run[mt] = mnew;
        l_run[mt] *= alpha;
        float af[4];
#pragma unroll
        for (int r = 0; r < 4; r++) af[r] = __shfl(alpha, rbase + r, 64);
#pragma unroll
        for (int nt = 0; nt < 4; nt++)
#pragma unroll
          for (int r = 0; r < 4; r++) o[mt][nt][r] *= af[r];
      }
      float rs = 0.f;
#pragma unroll
      for (int nt = 0; nt < 4; nt++)
#pragma unroll
        for (int r = 0; r < 4; r++) {
          float p = __builtin_amdgcn_exp2f(st[mt][nt][r] - m_run[mt]);
          st[mt][nt][r] = p;
          rs += p;
        }
      rs += __shfl_xor(rs, 16, 64);
      rs += __shfl_xor(rs, 32, 64);
      l_run[mt] += rs;

      // pack P row -> per-wave exchange buffer (word w=8nt+2q+h holds keys 2w,2w+1)
      unsigned int* pr = pw + ((mt * 16 + fr) << 5);
#pragma unroll
      for (int nt = 0; nt < 4; nt++)
#pragma unroll
        for (int hh = 0; hh < 2; hh++)
          pr[(((nt << 3) + (quad << 1) + hh)) ^ swz] =
              pk2(st[mt][nt][2 * hh], st[mt][nt][2 * hh + 1]);
    }

    // PV: A = P-frag (keys ks*32+quad*8 ..+7 of row mt*16+fr), B = V-frag from Vts
    short8 vf[4][2];
#pragma unroll
    for (int nt = 0; nt < 4; nt++)
#pragma unroll
      for (int ks = 0; ks < 2; ks++)
        vf[nt][ks] = *(const short8*)&Vts[(nt * 16 + fr) * 72 + ks * 32 + quad * 8];

    __builtin_amdgcn_s_setprio(1);
#pragma unroll
    for (int mt = 0; mt < 2; mt++) {
      const unsigned int* pr = pw + ((mt * 16 + fr) << 5);
      short8 pf[2];
#pragma unroll
      for (int ks = 0; ks < 2; ks++)
        pf[ks] = *(const short8*)&pr[((ks << 4) + (quad << 2)) ^ swz];
#pragma unroll
      for (int nt = 0; nt < 4; nt++) {
        o[mt][nt] = __builtin_amdgcn_mfma_f32_16x16x32_bf16(pf[0], vf[nt][0], o[mt][nt], 0, 0, 0);
        o[mt][nt] = __builtin_amdgcn_mfma_f32_16x16x32_bf16(pf[1], vf[nt][1], o[mt][nt], 0, 0, 0);
      }
    }
    __builtin_amdgcn_s_setprio(0);
  }

  // epilogue: o rows = wv*32 + mt*16 + quad*4 + r; pull 1/l from the lane owning that row
  size_t obase = ((size_t)b * T_SEQ + w * 256 + qh * 128 + wv * 32) * CDIM + h * HDIM;
#pragma unroll
  for (int mt = 0; mt < 2; mt++)
#pragma unroll
    for (int r = 0; r < 4; r++) {
      float lv = __shfl(l_run[mt], rbase + r, 64);
      float iv = 1.0f / fmaxf(lv, 1e-30f);
      int row = mt * 16 + quad * 4 + r;
#pragma unroll
      for (int nt = 0; nt < 4; nt++)
        AO[obase + (size_t)row * CDIM + nt * 16 + fr] = f2bf(o[mt][nt][r] * iv);
    }
}

extern "C" void kernel_launch(void* const* d_in, const int* in_sizes, int n_in,
                              void* d_out, int out_size, void* d_ws, size_t ws_size,
                              hipStream_t stream)
{
  const float* x    = (const float*)d_in[0];
  const int*   pm   = (const int*)d_in[1];
  const float* cosT = (const float*)d_in[2];
  const float* sinT = (const float*)d_in[3];
  const float* Wq   = (const float*)d_in[4];
  const float* bq   = (const float*)d_in[5];
  const float* Wk   = (const float*)d_in[6];
  const float* bk   = (const float*)d_in[7];
  const float* Wv   = (const float*)d_in[8];
  const float* bv   = (const float*)d_in[9];
  const float* Wo   = (const float*)d_in[10];
  const float* bo   = (const float*)d_in[11];
  float* out = (float*)d_out;

  static bool attr_done = false;
  if (!attr_done) {
    hipFuncSetAttribute(reinterpret_cast<const void*>(gemm_qkv),
                        hipFuncAttributeMaxDynamicSharedMemorySize, 131072);
    hipFuncSetAttribute(reinterpret_cast<const void*>(gemm_out),
                        hipFuncAttributeMaxDynamicSharedMemorySize, 131072);
    attr_done = true;
  }

  // scratch layout:
  //   d_out lower half : K (bf16)       — dead before final GEMM overwrites d_out
  //   d_out upper half : x_bf (bf16)    — dead after QKV projection
  //   ws: Wcat bf16 [Wq;Wk;Wv;Wo] (8 MB) + Q (33.5) + Vt (33.5, [b][ch][tok])
  const size_t NTOK = (size_t)B_SZ * T_SEQ;
  const size_t NELT = NTOK * CDIM;
  ushort_t* Kb  = (ushort_t*)d_out;
  ushort_t* xbf = (ushort_t*)d_out + NELT;
  char* ws = (char*)d_ws;
  ushort_t* Wbf = (ushort_t*)ws;
  ushort_t* Qb  = (ushort_t*)(ws + 4 * (size_t)CDIM * CDIM * 2);
  ushort_t* Vtb = Qb + NELT;
  ushort_t* AO  = Qb;             // AO aliases Q (per-block exclusive)

  cvt_f32_bf16<<<(int)(NELT / 4 / 256), 256, 0, stream>>>(x, xbf, (int)(NELT / 4));
  cvt_w4<<<dim3(CDIM * CDIM / 4 / 256, 4), 256, 0, stream>>>(Wq, Wk, Wv, Wo, Wbf);

  gemm_qkv<<<dim3(12, (int)(NTOK / 256)), 512, 67584, stream>>>(
      xbf, Wbf, bq, bk, bv, Qb, Kb, Vtb, cosT, sinT);

  attn_kernel<<<dim3(NH, NW * 2, B_SZ), 256, 0, stream>>>(Qb, Kb, Vtb, pm, AO);

  gemm_out<<<dim3(4, (int)(NTOK / 256)), 512, 65536, stream>>>(
      AO, Wbf + 3 * (size_t)CDIM * CDIM, bo, out);
}

// Round 10
// 404.720 us; speedup vs baseline: 1.3315x; 1.0447x over previous
//
#include <hip/hip_runtime.h>
#include <hip/hip_bf16.h>
#include <stdint.h>

#define T_SEQ 8192
#define B_SZ 2
#define CDIM 1024
#define NH 16
#define HDIM 64
#define NW 32

typedef unsigned short ushort_t;
typedef __attribute__((ext_vector_type(8))) short short8;     // 8 bf16 (4 VGPRs) MFMA A/B frag
typedef __attribute__((ext_vector_type(8))) unsigned short us8;
typedef __attribute__((ext_vector_type(4))) unsigned short us4;
typedef __attribute__((ext_vector_type(4))) float f32x4;      // MFMA C/D frag

__device__ __forceinline__ unsigned short f2bf(float f) {
  union { float f; unsigned int u; } c; c.f = f;
  return (unsigned short)((c.u + 0x7FFFu + ((c.u >> 16) & 1u)) >> 16);
}
__device__ __forceinline__ unsigned pk2(float a, float b) {
  unsigned r;
  asm("v_cvt_pk_bf16_f32 %0, %1, %2" : "=v"(r) : "v"(a), "v"(b));
  return r;   // low16 = bf16(a), high16 = bf16(b), RTNE
}
__device__ __forceinline__ void gld16(void* lds, const void* g) {
  __builtin_amdgcn_global_load_lds(
      (const __attribute__((address_space(1))) void*)g,
      (__attribute__((address_space(3))) void*)lds, 16, 0, 0);
}

// ---------------- fused fp32 -> bf16 conversion (x + all 4 weights, one dispatch) ----------
// blocks [0, nx4/256)           : x -> xbf
// blocks [nx4/256, +4096)       : Wq/Wk/Wv/Wo -> Wcat (1024 blocks per matrix, block-uniform)
__global__ __launch_bounds__(256) void cvt_all(const float* __restrict__ x,
                                               const float* __restrict__ w0,
                                               const float* __restrict__ w1,
                                               const float* __restrict__ w2,
                                               const float* __restrict__ w3,
                                               ushort_t* __restrict__ xbf,
                                               ushort_t* __restrict__ wbf,
                                               int nx4)
{
  int i = blockIdx.x * 256 + threadIdx.x;
  const float* src;
  ushort_t* dst;
  int idx;
  if (i < nx4) {
    src = x; dst = xbf; idx = i;
  } else {
    int j = i - nx4;              // 0 .. 4*262144-1
    int mat = j >> 18;            // 262144 float4 per 1024x1024 matrix (block-uniform)
    idx = j & 262143;
    src = (mat == 0) ? w0 : (mat == 1) ? w1 : (mat == 2) ? w2 : w3;
    dst = wbf + (size_t)mat * CDIM * CDIM;
  }
  float4 v = ((const float4*)src)[idx];
  ushort4 o;
  o.x = f2bf(v.x); o.y = f2bf(v.y); o.z = f2bf(v.z); o.w = f2bf(v.w);
  ((ushort4*)dst)[idx] = o;
}

// ---------------- 256x256 BK=64 double-buffered 2-phase GEMM core ----------------
// ROUND-5 EXACT (measured 129.9 us / 793 TF for qkv). Failed variants, do not re-try:
//   r6: counted-vmcnt + 2nd barrier graft  -> +7% (barrier overhead, no interleave)
//   r9: BK=32 + launch_bounds(512,2)       -> occupancy unchanged, bank conflicts, +4%
// 512 threads = 8 waves (2M x 4N). Per-wave output 128x64 (acc[8][4]).
// LDS (dynamic, 128 KB): As[2][256*64] + Bs[2][256*64], XOR-swizzled 16B blocks.
// Per K-tile: issue next tile's 8 gld16 FIRST, then ds_read+64 MFMA on current buffer,
// then one __syncthreads() (vmcnt0+lgkm0+barrier) — staging hides under compute.
__device__ __forceinline__ void gemm256_core(const ushort_t* __restrict__ A,
                                             const ushort_t* __restrict__ W,
                                             ushort_t* SH,
                                             int m0, int n0, int t, f32x4 acc[8][4])
{
  const int lane = t & 63;
  const int wv = t >> 6;          // 0..7
  const int wr = wv >> 2;         // 0..1  (M half)
  const int wc = wv & 3;          // 0..3  (N quarter)
  const int fr = lane & 15;
  const int quad = lane >> 4;

  ushort_t* As = SH;              // [2][16384]
  ushort_t* Bs = SH + 32768;

  const int sr8 = lane >> 3;                     // 0..7 == staged row & 7
  const int scb = ((lane & 7) ^ sr8) * 8;        // pre-swizzled source col (elems)
  const int srowb = wv * 8 + sr8;                // base staged row (0..63, +p*64)
  const ushort_t* Ag = A + (size_t)(m0 + srowb) * CDIM + scb;
  const ushort_t* Wg = W + (size_t)(n0 + srowb) * CDIM + scb;
  ushort_t* lA = As + srowb * 64 + (lane & 7) * 8;   // linear in lane within a wave
  ushort_t* lB = Bs + srowb * 64 + (lane & 7) * 8;

  // prologue: stage kt=0 into buf 0
#pragma unroll
  for (int p = 0; p < 4; p++) {
    gld16(lA + p * 4096, Ag + (size_t)p * 64 * CDIM);
    gld16(lB + p * 4096, Wg + (size_t)p * 64 * CDIM);
  }
  __syncthreads();

  for (int kt = 0; kt < CDIM / 64; ++kt) {
    const int cur = kt & 1;
    if (kt + 1 < CDIM / 64) {     // issue next tile BEFORE compute (latency hides under MFMA)
      const ushort_t* Agn = Ag + (kt + 1) * 64;
      const ushort_t* Wgn = Wg + (kt + 1) * 64;
      ushort_t* nA = lA + (cur ^ 1) * 16384;
      ushort_t* nB = lB + (cur ^ 1) * 16384;
#pragma unroll
      for (int p = 0; p < 4; p++) {
        gld16(nA + p * 4096, Agn + (size_t)p * 64 * CDIM);
        gld16(nB + p * 4096, Wgn + (size_t)p * 64 * CDIM);
      }
    }
    const ushort_t* Ac = As + cur * 16384;
    const ushort_t* Bc = Bs + cur * 16384;
    short8 b[4][2];
#pragma unroll
    for (int j = 0; j < 4; j++)
#pragma unroll
      for (int ks = 0; ks < 2; ks++)
        b[j][ks] = *(const short8*)&Bc[(wc * 64 + j * 16 + fr) * 64 +
                                       (((ks * 4 + quad) ^ (fr & 7)) * 8)];
    __builtin_amdgcn_s_setprio(1);
#pragma unroll
    for (int i = 0; i < 8; i++) {
      const int ra = (wr * 128 + i * 16 + fr) * 64;
      short8 a0 = *(const short8*)&Ac[ra + ((quad ^ (fr & 7)) * 8)];
      short8 a1 = *(const short8*)&Ac[ra + (((4 + quad) ^ (fr & 7)) * 8)];
#pragma unroll
      for (int j = 0; j < 4; j++)
        acc[i][j] = __builtin_amdgcn_mfma_f32_16x16x32_bf16(a0, b[j][0], acc[i][j], 0, 0, 0);
#pragma unroll
      for (int j = 0; j < 4; j++)
        acc[i][j] = __builtin_amdgcn_mfma_f32_16x16x32_bf16(a1, b[j][1], acc[i][j], 0, 0, 0);
    }
    __builtin_amdgcn_s_setprio(0);
    __syncthreads();              // vmcnt(0)+lgkmcnt(0)+barrier: next tile landed, reads done
  }
}

// XCD-chunked bijective block swizzle (nwg % 8 == 0 for all our grids)
__device__ __forceinline__ void xcd_swz(int& bx, int& by) {
  int gx = gridDim.x, nwg = gx * gridDim.y;
  int lid = bx + gx * by;
  int cpx = nwg >> 3;
  int swz = (lid & 7) * cpx + (lid >> 3);
  bx = swz % gx;
  by = swz / gx;
}

// ---------------- fused QKV projection: N=3072, per-section epilogue ----------------
// grid (12, 64), 512 threads, 128 KB dynamic LDS. sections: bx>>2 -> 0=Q 1=K 2=V.
__global__ __launch_bounds__(512, 1) void gemm_qkv(const ushort_t* __restrict__ A,
                                                   const ushort_t* __restrict__ Wcat,
                                                   const float* __restrict__ bq,
                                                   const float* __restrict__ bk,
                                                   const float* __restrict__ bv,
                                                   ushort_t* __restrict__ Qb,
                                                   ushort_t* __restrict__ Kb,
                                                   ushort_t* __restrict__ Vtb,
                                                   const float* __restrict__ cosT,
                                                   const float* __restrict__ sinT)
{
  extern __shared__ ushort_t SH[];   // 131072 B: K-loop dbuf tiles; epilogue 128x264 retile

  const int t = threadIdx.x;
  const int lane = t & 63;
  const int wv = t >> 6;
  const int wr = wv >> 2;
  const int wc = wv & 3;
  const int fr = lane & 15;
  const int quad = lane >> 4;
  int bx = blockIdx.x, by = blockIdx.y;
  xcd_swz(bx, by);
  const int m0 = by * 256;
  const int n0 = bx * 256;              // row in Wcat (0..3071)
  const int sec = bx >> 2;              // 0=Q 1=K 2=V
  const int nsec0 = (bx & 3) * 256;
  const float* bias = (sec == 0) ? bq : (sec == 1) ? bk : bv;

  f32x4 acc[8][4];
#pragma unroll
  for (int i = 0; i < 8; i++)
#pragma unroll
    for (int j = 0; j < 4; j++) acc[i][j] = (f32x4){0.f, 0.f, 0.f, 0.f};

  gemm256_core(A, Wcat, SH, m0, n0, t, acc);

  if (sec < 2) {
    // RoPE in C-layout regs -> LDS retile (stride 264) in two 128-row passes -> us8 stores
    ushort_t* OutQK = sec ? Kb : Qb;
#pragma unroll
    for (int half = 0; half < 2; ++half) {
      if (wr == half) {
#pragma unroll
        for (int jp = 0; jp < 2; jp++) {
          int d = jp * 16 + fr;               // head-dim lo (0..31)
          int cl = wc * 64 + jp * 16 + fr;    // col in 256-tile
          float bl = bias[nsec0 + cl];
          float bh = bias[nsec0 + cl + 32];
#pragma unroll
          for (int i = 0; i < 8; i++) {
            int rloc = i * 16 + quad * 4;     // row within the 128-row half
#pragma unroll
            for (int r = 0; r < 4; r++) {
              int m = m0 + half * 128 + rloc + r;
              int tt = m & (T_SEQ - 1);
              float c = cosT[tt * HDIM + d];
              float sn = sinT[tt * HDIM + d];
              float lo = acc[i][jp][r] + bl;
              float hi = acc[i][jp + 2][r] + bh;
              SH[(rloc + r) * 264 + cl] = f2bf(lo * c - hi * sn);
              SH[(rloc + r) * 264 + cl + 32] = f2bf(hi * c + lo * sn);
            }
          }
        }
      }
      __syncthreads();
      const int rr0 = t >> 5;                 // 0..15
      const int c8 = (t & 31) * 8;            // 0..248
      size_t gbase = (size_t)(m0 + half * 128) * CDIM + nsec0 + c8;
#pragma unroll
      for (int pp = 0; pp < 8; pp++) {
        int rr = pp * 16 + rr0;
        *(us8*)&OutQK[gbase + (size_t)rr * CDIM] = *(const us8*)&SH[rr * 264 + c8];
      }
      __syncthreads();
    }
  } else {
    // V -> Vt[b][ch][tok], 4 consecutive tokens per 8B store
#pragma unroll
    for (int j = 0; j < 4; j++) {
      int ch = nsec0 + wc * 64 + j * 16 + fr;
      float bvv = bias[ch];
#pragma unroll
      for (int i = 0; i < 8; i++) {
        int m = m0 + wr * 128 + i * 16 + quad * 4;
        int bb = m >> 13;
        int tq = m & (T_SEQ - 1);
        us4 pk;
#pragma unroll
        for (int r = 0; r < 4; r++) pk[r] = f2bf(acc[i][j][r] + bvv);
        *(us4*)&Vtb[((size_t)bb * CDIM + ch) * T_SEQ + tq] = pk;
      }
    }
  }
}

// ---------------- output projection: bf16 in, fp32 out; grid (4, 64) ----------------
__global__ __launch_bounds__(512, 1) void gemm_out(const ushort_t* __restrict__ A,
                                                   const ushort_t* __restrict__ W,
                                                   const float* __restrict__ bias,
                                                   float* __restrict__ Out)
{
  extern __shared__ ushort_t SH[];

  const int t = threadIdx.x;
  const int lane = t & 63;
  const int wv = t >> 6;
  const int wr = wv >> 2;
  const int wc = wv & 3;
  const int fr = lane & 15;
  const int quad = lane >> 4;
  int bx = blockIdx.x, by = blockIdx.y;
  xcd_swz(bx, by);
  const int m0 = by * 256;
  const int n0 = bx * 256;

  f32x4 acc[8][4];
#pragma unroll
  for (int i = 0; i < 8; i++)
#pragma unroll
    for (int j = 0; j < 4; j++) acc[i][j] = (f32x4){0.f, 0.f, 0.f, 0.f};

  gemm256_core(A, W, SH, m0, n0, t, acc);

#pragma unroll
  for (int j = 0; j < 4; j++) {
    int n = n0 + wc * 64 + j * 16 + fr;
    float bvv = bias[n];
#pragma unroll
    for (int i = 0; i < 8; i++) {
      int m = m0 + wr * 128 + i * 16 + quad * 4;
#pragma unroll
      for (int r = 0; r < 4; r++)
        Out[(size_t)(m + r) * CDIM + n] = acc[i][j][r] + bvv;
    }
  }
}

// ---------------- windowed attention (round-5 config EXACT — frozen) ----------------
// r2/r7/r8 all showed: any change to attn's grid order, residency, or liveness pattern
// collapses the inter-block L2 reuse of the shared K/V streams (FETCH 2-5x). Do not touch.
__global__ __launch_bounds__(256, 4) void attn_kernel(const ushort_t* __restrict__ Q,
                                                      const ushort_t* __restrict__ Kg,
                                                      const ushort_t* __restrict__ Vt,
                                                      const int* __restrict__ mask,
                                                      ushort_t* __restrict__ AO)
{
  __shared__ ushort_t Ks[64 * 72];            //  9216 B  [key][dim]
  __shared__ ushort_t Vts[64 * 72];           //  9216 B  [dim][key]
  __shared__ unsigned int PsW[4 * 32 * 32];   // 16384 B  per-wave 32 rows x 32 words, XOR-swz
  __shared__ float attf[512];                 //  2048 B  additive key bias (0 / -1e38)

  const int t = threadIdx.x;
  const int lane = t & 63;
  const int wv = t >> 6;
  const int h = blockIdx.x;
  const int w = blockIdx.y >> 1;
  const int qh = blockIdx.y & 1;
  const int b = blockIdx.z;
  const int fr = lane & 15;
  const int quad = lane >> 4;

  {
    int p0 = w * 256 + t - 128;
    bool a0 = (p0 < 0 || p0 >= T_SEQ) ? true : (mask[b * T_SEQ + p0] == 0);
    int p1 = p0 + 256;
    bool a1 = (p1 < 0 || p1 >= T_SEQ) ? true : (mask[b * T_SEQ + p1] == 0);
    int all1 = __syncthreads_and((int)(a0 && a1));
    attf[t] = a0 ? 0.f : -1.0e38f;
    attf[t + 256] = a1 ? 0.f : -1.0e38f;
    if (all1 && t == 0) attf[0] = -1.0e38f;   // reference quirk: fully-attendable -> mask key 0
  }

  // Q -> registers (B-frag of QK^T): lane holds Q[mt*16+fr][ks*32+quad*8 ..+7]
  short8 qf[2][2];
  {
    const ushort_t* qp = Q + ((size_t)b * T_SEQ + w * 256 + qh * 128 + wv * 32 + fr) * CDIM
                           + h * HDIM + quad * 8;
#pragma unroll
    for (int mt = 0; mt < 2; mt++)
#pragma unroll
      for (int ks = 0; ks < 2; ks++)
        qf[mt][ks] = *(const short8*)&qp[(size_t)mt * 16 * CDIM + ks * 32];
  }

  const int srow = t >> 3;                    // 0..31
  const int sc8 = (t & 7) * 8;
  const ushort_t* kgb = Kg + (size_t)b * T_SEQ * CDIM + h * HDIM + sc8;
  const ushort_t* vt_base = Vt + ((size_t)b * CDIM + h * HDIM) * T_SEQ;
  const float SCL = 0.18033688011112042f;     // 0.125 * log2(e)

  unsigned int* pw = &PsW[wv * 1024];
  const int swz = (fr & 7) << 2;
  const int rbase = quad << 2;

  float m_run[2], l_run[2];
  f32x4 o[2][4];
#pragma unroll
  for (int mt = 0; mt < 2; mt++) { m_run[mt] = -3.0e38f; l_run[mt] = 0.f; }
#pragma unroll
  for (int mt = 0; mt < 2; mt++)
#pragma unroll
    for (int nt = 0; nt < 4; nt++) o[mt][nt] = (f32x4){0.f, 0.f, 0.f, 0.f};

  for (int kc = 0; kc < 8; kc++) {
    __syncthreads();
    {
#pragma unroll
      for (int p = 0; p < 2; p++) {
        int jj = p * 32 + srow;
        int pos = w * 256 + kc * 64 + jj - 128;
        us8 kval = (us8)(0);
        if (pos >= 0 && pos < T_SEQ) kval = *(const us8*)&kgb[(size_t)pos * CDIM];
        *(us8*)&Ks[jj * 72 + sc8] = kval;
      }
      int pos0 = w * 256 + kc * 64 - 128 + sc8;
      bool inr = (pos0 >= 0) && (pos0 < T_SEQ);
#pragma unroll
      for (int p = 0; p < 2; p++) {
        int d = p * 32 + srow;
        us8 vv = (us8)(0);
        if (inr) vv = *(const us8*)&vt_base[(size_t)d * T_SEQ + pos0];
        *(us8*)&Vts[d * 72 + sc8] = vv;
      }
    }
    __syncthreads();

    // S^T = K·Q^T : lane holds key = nt*16+quad*4+r, q-row = mt*16+fr
    short8 kf[4][2];
#pragma unroll
    for (int nt = 0; nt < 4; nt++)
#pragma unroll
      for (int ks = 0; ks < 2; ks++)
        kf[nt][ks] = *(const short8*)&Ks[(nt * 16 + fr) * 72 + ks * 32 + quad * 8];

    f32x4 st[2][4];
    __builtin_amdgcn_s_setprio(1);
#pragma unroll
    for (int mt = 0; mt < 2; mt++)
#pragma unroll
      for (int nt = 0; nt < 4; nt++) {
        f32x4 a = (f32x4){0.f, 0.f, 0.f, 0.f};
        a = __builtin_amdgcn_mfma_f32_16x16x32_bf16(kf[nt][0], qf[mt][0], a, 0, 0, 0);
        a = __builtin_amdgcn_mfma_f32_16x16x32_bf16(kf[nt][1], qf[mt][1], a, 0, 0, 0);
        st[mt][nt] = a;
      }
    __builtin_amdgcn_s_setprio(0);

    // scale + mask fused (exp2 domain); kb[nt][r] is key 16nt+4*quad+r
    f32x4 kb[4];
#pragma unroll
    for (int nt = 0; nt < 4; nt++)
      kb[nt] = *(const f32x4*)&attf[kc * 64 + nt * 16 + quad * 4];
#pragma unroll
    for (int mt = 0; mt < 2; mt++)
#pragma unroll
      for (int nt = 0; nt < 4; nt++)
#pragma unroll
        for (int r = 0; r < 4; r++)
          st[mt][nt][r] = __builtin_fmaf(st[mt][nt][r], SCL, kb[nt][r]);

    // lane-local online softmax (rows mt*16+fr), defer-max THR=8
#pragma unroll
    for (int mt = 0; mt < 2; mt++) {
      float t0 = fmaxf(fmaxf(st[mt][0][0], st[mt][0][1]), fmaxf(st[mt][0][2], st[mt][0][3]));
      float t1 = fmaxf(fmaxf(st[mt][1][0], st[mt][1][1]), fmaxf(st[mt][1][2], st[mt][1][3]));
      float t2 = fmaxf(fmaxf(st[mt][2][0], st[mt][2][1]), fmaxf(st[mt][2][2], st[mt][2][3]));
      float t3 = fmaxf(fmaxf(st[mt][3][0], st[mt][3][1]), fmaxf(st[mt][3][2], st[mt][3][3]));
      float mx = fmaxf(fmaxf(t0, t1), fmaxf(t2, t3));
      mx = fmaxf(mx, __shfl_xor(mx, 16, 64));
      mx = fmaxf(mx, __shfl_xor(mx, 32, 64));
      if (!__all(mx <= m_run[mt] + 8.f)) {
        float mnew = fmaxf(m_run[mt], mx);
        float alpha = __builtin_amdgcn_exp2f(m_run[mt] - mnew);
        m_run[mt] = mnew;
        l_run[mt] *= alpha;
        float af[4];
#pragma unroll
        for (int r = 0; r < 4; r++) af[r] = __shfl(alpha, rbase + r, 64);
#pragma unroll
        for (int nt = 0; nt < 4; nt++)
#pragma unroll
          for (int r = 0; r < 4; r++) o[mt][nt][r] *= af[r];
      }
      float rs = 0.f;
#pragma unroll
      for (int nt = 0; nt < 4; nt++)
#pragma unroll
        for (int r = 0; r < 4; r++) {
          float p = __builtin_amdgcn_exp2f(st[mt][nt][r] - m_run[mt]);
          st[mt][nt][r] = p;
          rs += p;
        }
      rs += __shfl_xor(rs, 16, 64);
      rs += __shfl_xor(rs, 32, 64);
      l_run[mt] += rs;

      // pack P row -> per-wave exchange buffer (word w=8nt+2q+h holds keys 2w,2w+1)
      unsigned int* pr = pw + ((mt * 16 + fr) << 5);
#pragma unroll
      for (int nt = 0; nt < 4; nt++)
#pragma unroll
        for (int hh = 0; hh < 2; hh++)
          pr[(((nt << 3) + (quad << 1) + hh)) ^ swz] =
              pk2(st[mt][nt][2 * hh], st[mt][nt][2 * hh + 1]);
    }

    // PV: A = P-frag (keys ks*32+quad*8 ..+7 of row mt*16+fr), B = V-frag from Vts
    short8 vf[4][2];
#pragma unroll
    for (int nt = 0; nt < 4; nt++)
#pragma unroll
      for (int ks = 0; ks < 2; ks++)
        vf[nt][ks] = *(const short8*)&Vts[(nt * 16 + fr) * 72 + ks * 32 + quad * 8];

    __builtin_amdgcn_s_setprio(1);
#pragma unroll
    for (int mt = 0; mt < 2; mt++) {
      const unsigned int* pr = pw + ((mt * 16 + fr) << 5);
      short8 pf[2];
#pragma unroll
      for (int ks = 0; ks < 2; ks++)
        pf[ks] = *(const short8*)&pr[((ks << 4) + (quad << 2)) ^ swz];
#pragma unroll
      for (int nt = 0; nt < 4; nt++) {
        o[mt][nt] = __builtin_amdgcn_mfma_f32_16x16x32_bf16(pf[0], vf[nt][0], o[mt][nt], 0, 0, 0);
        o[mt][nt] = __builtin_amdgcn_mfma_f32_16x16x32_bf16(pf[1], vf[nt][1], o[mt][nt], 0, 0, 0);
      }
    }
    __builtin_amdgcn_s_setprio(0);
  }

  // epilogue: o rows = wv*32 + mt*16 + quad*4 + r; pull 1/l from the lane owning that row
  size_t obase = ((size_t)b * T_SEQ + w * 256 + qh * 128 + wv * 32) * CDIM + h * HDIM;
#pragma unroll
  for (int mt = 0; mt < 2; mt++)
#pragma unroll
    for (int r = 0; r < 4; r++) {
      float lv = __shfl(l_run[mt], rbase + r, 64);
      float iv = 1.0f / fmaxf(lv, 1e-30f);
      int row = mt * 16 + quad * 4 + r;
#pragma unroll
      for (int nt = 0; nt < 4; nt++)
        AO[obase + (size_t)row * CDIM + nt * 16 + fr] = f2bf(o[mt][nt][r] * iv);
    }
}

extern "C" void kernel_launch(void* const* d_in, const int* in_sizes, int n_in,
                              void* d_out, int out_size, void* d_ws, size_t ws_size,
                              hipStream_t stream)
{
  const float* x    = (const float*)d_in[0];
  const int*   pm   = (const int*)d_in[1];
  const float* cosT = (const float*)d_in[2];
  const float* sinT = (const float*)d_in[3];
  const float* Wq   = (const float*)d_in[4];
  const float* bq   = (const float*)d_in[5];
  const float* Wk   = (const float*)d_in[6];
  const float* bk   = (const float*)d_in[7];
  const float* Wv   = (const float*)d_in[8];
  const float* bv   = (const float*)d_in[9];
  const float* Wo   = (const float*)d_in[10];
  const float* bo   = (const float*)d_in[11];
  float* out = (float*)d_out;

  static bool attr_done = false;
  if (!attr_done) {
    hipFuncSetAttribute(reinterpret_cast<const void*>(gemm_qkv),
                        hipFuncAttributeMaxDynamicSharedMemorySize, 131072);
    hipFuncSetAttribute(reinterpret_cast<const void*>(gemm_out),
                        hipFuncAttributeMaxDynamicSharedMemorySize, 131072);
    attr_done = true;
  }

  // scratch layout:
  //   d_out lower half : K (bf16)       — dead before final GEMM overwrites d_out
  //   d_out upper half : x_bf (bf16)    — dead after QKV projection
  //   ws: Wcat bf16 [Wq;Wk;Wv;Wo] (8 MB) + Q (33.5) + Vt (33.5, [b][ch][tok])
  const size_t NTOK = (size_t)B_SZ * T_SEQ;
  const size_t NELT = NTOK * CDIM;
  ushort_t* Kb  = (ushort_t*)d_out;
  ushort_t* xbf = (ushort_t*)d_out + NELT;
  char* ws = (char*)d_ws;
  ushort_t* Wbf = (ushort_t*)ws;
  ushort_t* Qb  = (ushort_t*)(ws + 4 * (size_t)CDIM * CDIM * 2);
  ushort_t* Vtb = Qb + NELT;
  ushort_t* AO  = Qb;             // AO aliases Q (per-block exclusive)

  const int nx4 = (int)(NELT / 4);                 // 4,194,304 x-float4s
  const int nblk = (nx4 + 4 * (CDIM * CDIM / 4)) / 256;   // + 1,048,576 weight-float4s
  cvt_all<<<nblk, 256, 0, stream>>>(x, Wq, Wk, Wv, Wo, xbf, Wbf, nx4);

  gemm_qkv<<<dim3(12, (int)(NTOK / 256)), 512, 131072, stream>>>(
      xbf, Wbf, bq, bk, bv, Qb, Kb, Vtb, cosT, sinT);

  attn_kernel<<<dim3(NH, NW * 2, B_SZ), 256, 0, stream>>>(Qb, Kb, Vtb, pm, AO);

  gemm_out<<<dim3(4, (int)(NTOK / 256)), 512, 131072, stream>>>(
      AO, Wbf + 3 * (size_t)CDIM * CDIM, bo, out);
}